// Round 17
// baseline (677.309 us; speedup 1.0000x reference)
//
#include <hip/hip_runtime.h>
#include <hip/hip_bf16.h>

#define NC 200000
#define NCP 200064
#define NCT 1563
#define NRG 196
#define CTR 8
#define SCAP2 32
#define CROW (NRG * SCAP2)   // 6272 slots per row
#define SREG 25              // ceil(6272/256)
#define BB 1024
#define DD 128
#define DBH 256
#define CS 96

typedef __attribute__((ext_vector_type(8))) short bf16x8;
typedef __attribute__((ext_vector_type(4))) float f32x4;

#define LDH 136
#define LDU 264

__device__ inline uint4 pack8(const float4 a, const float4 b) {
  union { __hip_bfloat16 h[8]; uint4 v; } r;
  r.h[0] = __float2bfloat16(a.x); r.h[1] = __float2bfloat16(a.y);
  r.h[2] = __float2bfloat16(a.z); r.h[3] = __float2bfloat16(a.w);
  r.h[4] = __float2bfloat16(b.x); r.h[5] = __float2bfloat16(b.y);
  r.h[6] = __float2bfloat16(b.z); r.h[7] = __float2bfloat16(b.w);
  return r.v;
}

__device__ inline unsigned encf(float v) {
  unsigned b = __float_as_uint(v);
  return (b & 0x80000000u) ? ~b : (b | 0x80000000u);
}
__device__ inline float decf(unsigned u) {
  return __uint_as_float((u & 0x80000000u) ? (u ^ 0x80000000u) : ~u);
}
// key: high32 = ~enc(v)  (u64-ascending == value-descending), low32 = idx
__device__ inline unsigned long long mkkey(float v, int idx) {
  unsigned u = encf(v);
  return (((unsigned long long)(~u)) << 32) | (unsigned)idx;
}

// async 16B global -> LDS (wave-uniform LDS base + lane*16)
__device__ inline void gload16(const void* g, void* l) {
  __builtin_amdgcn_global_load_lds((const __attribute__((address_space(1))) void*)g,
                                   (__attribute__((address_space(3))) void*)l, 16, 0, 0);
}

// ====================== weight prep: bf16 transposed copies ======================
__global__ __launch_bounds__(256) void k_prep(const float* __restrict__ w1,
                                              const float* __restrict__ w2,
                                              const float* __restrict__ kw,
                                              const float* __restrict__ tw1,
                                              __hip_bfloat16* __restrict__ w1t,
                                              __hip_bfloat16* __restrict__ w2t,
                                              __hip_bfloat16* __restrict__ kwt,
                                              __hip_bfloat16* __restrict__ tw1t) {
  const int i = blockIdx.x * 256 + threadIdx.x;
  if (i < 32768) {
    const int u = i >> 7, j = i & 127;
    w1t[i] = __float2bfloat16(w1[j * DBH + u]);
    tw1t[i] = __float2bfloat16(tw1[j * DBH + u]);
  }
  if (i < 32768) {
    const int d = i >> 8, u = i & 255;
    w2t[i] = __float2bfloat16(w2[u * DD + d]);
  }
  if (i < 16384) {
    const int d = i >> 7, j = i & 127;
    kwt[i] = __float2bfloat16(kw[j * DD + d]);
  }
}

// ================= pad rows [NC, NCP): zero keys, huge ck2 (scores ~ -5e8) =================
__global__ __launch_bounds__(256) void k_pad(__hip_bfloat16* __restrict__ ckb16,
                                             float* __restrict__ ck2) {
  const int i = blockIdx.x * 256 + threadIdx.x;
  if (i < (NCP - NC) * DD) ckb16[(size_t)NC * DD + i] = __float2bfloat16(0.f);
  if (i < (NCP - NC)) ck2[NC + i] = 1e9f;
}

// ======= fused encoder: H=X@Win+b; H+=MLP(H); K=LN(H)@Kw+Kb; outputs K f32/bf16, k2, (H) =======
__global__ __launch_bounds__(256) void k_encf(const float* __restrict__ X,
                                              const float* __restrict__ Win,
                                              const float* __restrict__ bin,
                                              const __hip_bfloat16* __restrict__ W1t,
                                              const float* __restrict__ B1,
                                              const __hip_bfloat16* __restrict__ W2t,
                                              const float* __restrict__ B2,
                                              const float* __restrict__ g,
                                              const float* __restrict__ bln,
                                              const __hip_bfloat16* __restrict__ Kwt,
                                              const float* __restrict__ Kb,
                                              float* __restrict__ Kout,
                                              __hip_bfloat16* __restrict__ Kb16,
                                              float* __restrict__ k2out,
                                              float* __restrict__ Hout) {
  __shared__ float Xs[64 * 36];              // 9.2 KB, stride-36 (2-way-free banks)
  __shared__ float Ws[32 * 128];             // 16 KB
  __shared__ __hip_bfloat16 Hs[64 * LDH];    // 17.4 KB
  __shared__ __hip_bfloat16 Us[64 * LDU];    // 33.8 KB (reused as Ls)
  __shared__ float redS[4 * 64];             // 1 KB
  __shared__ float k2s[64];
  const int tid = threadIdx.x;
  const int r0 = blockIdx.x * 64;
  const int l = tid & 63, w = tid >> 6;
  const int lr = l & 15, lg = l >> 4;
  if (tid < 64) k2s[tid] = 0.f;
  {  // stage X (64x32 f32) and Win (32x128 f32)
    const float4* gx = (const float4*)(X + (size_t)r0 * 32);
#pragma unroll
    for (int i = 0; i < 2; ++i) {
      const int e4 = tid + 256 * i;
      const int row = e4 >> 3, c4 = e4 & 7;
      ((float4*)Xs)[row * 9 + c4] = gx[e4];
    }
    const float4* gw = (const float4*)Win;
#pragma unroll
    for (int i = 0; i < 4; ++i) ((float4*)Ws)[tid + 256 * i] = gw[tid + 256 * i];
  }
  __syncthreads();
  // ---- phase 1 (e1): Hreg[mi][r][ni] at (row=mi*16+lg*4+r, col=w*32+ni*16+lr) ----
  float Hreg[4][4][2];
#pragma unroll
  for (int ni = 0; ni < 2; ++ni) {
    const int col = w * 32 + ni * 16 + lr;
    const float bb = bin[col];
    float wc[32];
#pragma unroll
    for (int k = 0; k < 32; ++k) wc[k] = Ws[k * 128 + col];
#pragma unroll
    for (int mi = 0; mi < 4; ++mi)
#pragma unroll
      for (int r = 0; r < 4; ++r) {
        const int row = mi * 16 + lg * 4 + r;
        const float* xr = Xs + row * 36;
        float s = bb;
#pragma unroll
        for (int k = 0; k < 32; ++k) s += xr[k] * wc[k];
        Hreg[mi][r][ni] = s;
        Hs[row * LDH + col] = __float2bfloat16(s);
      }
  }
  __syncthreads();
  // ---- phase 2 (e23 p1): Us = relu(Hs @ W1 + b1) ----
  {
    f32x4 acc[4][4] = {};
#pragma unroll
    for (int kk = 0; kk < 4; ++kk) {
      bf16x8 a[4], b[4];
#pragma unroll
      for (int mi = 0; mi < 4; ++mi)
        a[mi] = *(const bf16x8*)(Hs + (mi * 16 + lr) * LDH + kk * 32 + lg * 8);
#pragma unroll
      for (int ni = 0; ni < 4; ++ni)
        b[ni] = *(const bf16x8*)(W1t + (size_t)(w * 64 + ni * 16 + lr) * DD + kk * 32 + lg * 8);
#pragma unroll
      for (int mi = 0; mi < 4; ++mi)
#pragma unroll
        for (int ni = 0; ni < 4; ++ni)
          acc[mi][ni] = __builtin_amdgcn_mfma_f32_16x16x32_bf16(a[mi], b[ni], acc[mi][ni], 0, 0, 0);
    }
    __syncthreads();   // Hs reads done (Us and Hs disjoint, but keep write order clean)
#pragma unroll
    for (int ni = 0; ni < 4; ++ni) {
      const int col = w * 64 + ni * 16 + lr;
      const float bb = B1[col];
#pragma unroll
      for (int mi = 0; mi < 4; ++mi)
#pragma unroll
        for (int r = 0; r < 4; ++r) {
          const int row = mi * 16 + lg * 4 + r;
          Us[row * LDU + col] = __float2bfloat16(fmaxf(acc[mi][ni][r] + bb, 0.f));
        }
    }
  }
  __syncthreads();
  // ---- phase 3 (e23 p2): Hreg += Us @ W2 + b2 (in registers; no global H) ----
  {
    f32x4 acc[4][2] = {};
#pragma unroll
    for (int kk = 0; kk < 8; ++kk) {
      bf16x8 a[4], b[2];
#pragma unroll
      for (int mi = 0; mi < 4; ++mi)
        a[mi] = *(const bf16x8*)(Us + (mi * 16 + lr) * LDU + kk * 32 + lg * 8);
#pragma unroll
      for (int ni = 0; ni < 2; ++ni)
        b[ni] = *(const bf16x8*)(W2t + (size_t)(w * 32 + ni * 16 + lr) * DBH + kk * 32 + lg * 8);
#pragma unroll
      for (int mi = 0; mi < 4; ++mi)
#pragma unroll
        for (int ni = 0; ni < 2; ++ni)
          acc[mi][ni] = __builtin_amdgcn_mfma_f32_16x16x32_bf16(a[mi], b[ni], acc[mi][ni], 0, 0, 0);
    }
#pragma unroll
    for (int ni = 0; ni < 2; ++ni) {
      const float bb = B2[w * 32 + ni * 16 + lr];
#pragma unroll
      for (int mi = 0; mi < 4; ++mi)
#pragma unroll
        for (int r = 0; r < 4; ++r)
          Hreg[mi][r][ni] += acc[mi][ni][r] + bb;
    }
  }
  // optional H output (queries)
  if (Hout) {
#pragma unroll
    for (int ni = 0; ni < 2; ++ni) {
      const int col = w * 32 + ni * 16 + lr;
#pragma unroll
      for (int mi = 0; mi < 4; ++mi)
#pragma unroll
        for (int r = 0; r < 4; ++r)
          Hout[(size_t)(r0 + mi * 16 + lg * 4 + r) * DD + col] = Hreg[mi][r][ni];
    }
  }
  __syncthreads();   // Us reads of phase 3 done before Ls reuse
  // ---- phase 4 (LN stats): mean/var per row via shfl(16-lane) + LDS cross-wave ----
  float mean_[4][4], rstd_[4][4];
#pragma unroll
  for (int mi = 0; mi < 4; ++mi)
#pragma unroll
    for (int r = 0; r < 4; ++r) {
      float ps = Hreg[mi][r][0] + Hreg[mi][r][1];
      ps += __shfl_xor(ps, 1); ps += __shfl_xor(ps, 2);
      ps += __shfl_xor(ps, 4); ps += __shfl_xor(ps, 8);
      if (lr == 0) redS[w * 64 + mi * 16 + lg * 4 + r] = ps;
    }
  __syncthreads();
#pragma unroll
  for (int mi = 0; mi < 4; ++mi)
#pragma unroll
    for (int r = 0; r < 4; ++r) {
      const int row = mi * 16 + lg * 4 + r;
      mean_[mi][r] = (redS[row] + redS[64 + row] + redS[128 + row] + redS[192 + row]) * (1.f / 128.f);
    }
  __syncthreads();
#pragma unroll
  for (int mi = 0; mi < 4; ++mi)
#pragma unroll
    for (int r = 0; r < 4; ++r) {
      const float d0 = Hreg[mi][r][0] - mean_[mi][r];
      const float d1 = Hreg[mi][r][1] - mean_[mi][r];
      float ps = d0 * d0 + d1 * d1;
      ps += __shfl_xor(ps, 1); ps += __shfl_xor(ps, 2);
      ps += __shfl_xor(ps, 4); ps += __shfl_xor(ps, 8);
      if (lr == 0) redS[w * 64 + mi * 16 + lg * 4 + r] = ps;
    }
  __syncthreads();
#pragma unroll
  for (int mi = 0; mi < 4; ++mi)
#pragma unroll
    for (int r = 0; r < 4; ++r) {
      const int row = mi * 16 + lg * 4 + r;
      const float v = (redS[row] + redS[64 + row] + redS[128 + row] + redS[192 + row]) * (1.f / 128.f);
      rstd_[mi][r] = 1.f / sqrtf(v + 1e-5f);
    }
  // ---- phase 5: Ls (LN output, bf16) into the dead Us region ----
  __hip_bfloat16* Ls = Us;
#pragma unroll
  for (int ni = 0; ni < 2; ++ni) {
    const int col = w * 32 + ni * 16 + lr;
    const float gc = g[col], bc = bln[col];
#pragma unroll
    for (int mi = 0; mi < 4; ++mi)
#pragma unroll
      for (int r = 0; r < 4; ++r) {
        const int row = mi * 16 + lg * 4 + r;
        const float val = (Hreg[mi][r][ni] - mean_[mi][r]) * rstd_[mi][r] * gc + bc;
        Ls[row * LDH + col] = __float2bfloat16(val);
      }
  }
  __syncthreads();
  // ---- phase 6 (e4): K = Ls @ Kw + Kb ; outputs + rowwise k^2 ----
  {
    f32x4 acc[4][2] = {};
#pragma unroll
    for (int kk = 0; kk < 4; ++kk) {
      bf16x8 a[4], b[2];
#pragma unroll
      for (int mi = 0; mi < 4; ++mi)
        a[mi] = *(const bf16x8*)(Ls + (mi * 16 + lr) * LDH + kk * 32 + lg * 8);
#pragma unroll
      for (int ni = 0; ni < 2; ++ni)
        b[ni] = *(const bf16x8*)(Kwt + (size_t)(w * 32 + ni * 16 + lr) * DD + kk * 32 + lg * 8);
#pragma unroll
      for (int mi = 0; mi < 4; ++mi)
#pragma unroll
        for (int ni = 0; ni < 2; ++ni)
          acc[mi][ni] = __builtin_amdgcn_mfma_f32_16x16x32_bf16(a[mi], b[ni], acc[mi][ni], 0, 0, 0);
    }
    float p[4][4];
#pragma unroll
    for (int mi = 0; mi < 4; ++mi)
#pragma unroll
      for (int r = 0; r < 4; ++r) p[mi][r] = 0.f;
#pragma unroll
    for (int ni = 0; ni < 2; ++ni) {
      const int col = w * 32 + ni * 16 + lr;
      const float kb = Kb[col];
#pragma unroll
      for (int mi = 0; mi < 4; ++mi)
#pragma unroll
        for (int r = 0; r < 4; ++r) {
          const float val = acc[mi][ni][r] + kb;
          const int row = mi * 16 + lg * 4 + r;
          const size_t gg = (size_t)(r0 + row) * DD + col;
          Kout[gg] = val;
          Kb16[gg] = __float2bfloat16(val);
          p[mi][r] += val * val;
        }
    }
#pragma unroll
    for (int mi = 0; mi < 4; ++mi)
#pragma unroll
      for (int r = 0; r < 4; ++r) {
        float t = p[mi][r];
        t += __shfl_xor(t, 1); t += __shfl_xor(t, 2);
        t += __shfl_xor(t, 4); t += __shfl_xor(t, 8);
        if (lr == 0) atomicAdd(&k2s[mi * 16 + lg * 4 + r], t);
      }
  }
  __syncthreads();
  if (tid < 64) k2out[r0 + tid] = k2s[tid];
}

// ==== pass 1: block=(rowtile, range); XCD-affine; B via global_load_lds + XOR swizzle ====
__global__ __launch_bounds__(256) void k_simsA(const __hip_bfloat16* __restrict__ A,
                                               const __hip_bfloat16* __restrict__ Bm,
                                               const float* __restrict__ ck2,
                                               float* __restrict__ rmaxpart) {
  __shared__ __hip_bfloat16 Bs[128 * 128];   // linear 32 KB, content XOR-swizzled per row
  __shared__ float part[2][128];
  const int tid = threadIdx.x;
  const int bid = blockIdx.x;         // grid 1600 = 25 x 8rt x 8x
  const int gq = bid >> 6, rt = (bid >> 3) & 7, xq = bid & 7;
  const int range = gq * 8 + xq;
  if (range >= NRG) return;
  const int m0 = rt * 128;
  const int l = tid & 63, w = tid >> 6;
  const int wm = w >> 1, wn = w & 1;
  const int lr = l & 15, lg = l >> 4;
  bf16x8 a[4][4];
#pragma unroll
  for (int mi = 0; mi < 4; ++mi) {
    const __hip_bfloat16* ar = A + (size_t)(m0 + wm * 64 + mi * 16 + lr) * DD + lg * 8;
#pragma unroll
    for (int kk = 0; kk < 4; ++kk) a[mi][kk] = *(const bf16x8*)(ar + kk * 32);
  }
  float vmax[4][4];
#pragma unroll
  for (int mi = 0; mi < 4; ++mi)
#pragma unroll
    for (int r = 0; r < 4; ++r) vmax[mi][r] = -1e30f;
  for (int i = 0; i < CTR; ++i) {
    const int ct = range * CTR + i;
    if (ct >= NCT) break;
    const int n0 = ct * 128;
    {  // async staged, source pre-swizzled so swizzled read is conflict-free
      const char* gbase = (const char*)(Bm + (size_t)n0 * DD);
#pragma unroll
      for (int j = 0; j < 8; ++j) {
        const int r = w * 32 + j * 4 + (l >> 4);
        const int b = ((l & 15) * 16) ^ ((r & 7) << 4);
        gload16(gbase + (size_t)r * 256 + b, (char*)Bs + w * 8192 + j * 1024);
      }
    }
    float c2l[4];
#pragma unroll
    for (int ni = 0; ni < 4; ++ni) c2l[ni] = 0.5f * ck2[n0 + wn * 64 + ni * 16 + lr];
    __syncthreads();
    f32x4 acc[4][4] = {};
#pragma unroll
    for (int kk = 0; kk < 4; ++kk) {
      bf16x8 b[4];
#pragma unroll
      for (int ni = 0; ni < 4; ++ni) {
        const int row = wn * 64 + ni * 16 + lr;
        const int boff = (kk * 64 + lg * 16) ^ ((row & 7) << 4);
        b[ni] = *(const bf16x8*)((const char*)Bs + row * 256 + boff);
      }
#pragma unroll
      for (int mi = 0; mi < 4; ++mi)
#pragma unroll
        for (int ni = 0; ni < 4; ++ni)
          acc[mi][ni] = __builtin_amdgcn_mfma_f32_16x16x32_bf16(a[mi][kk], b[ni], acc[mi][ni], 0, 0, 0);
    }
#pragma unroll
    for (int mi = 0; mi < 4; ++mi)
#pragma unroll
      for (int r = 0; r < 4; ++r)
#pragma unroll
        for (int ni = 0; ni < 4; ++ni)
          vmax[mi][r] = fmaxf(vmax[mi][r], acc[mi][ni][r] - c2l[ni]);
    __syncthreads();
  }
#pragma unroll
  for (int mi = 0; mi < 4; ++mi)
#pragma unroll
    for (int r = 0; r < 4; ++r) {
      float v = vmax[mi][r];
#pragma unroll
      for (int mk = 1; mk < 16; mk <<= 1) v = fmaxf(v, __shfl_xor(v, mk));
      if (lr == 0) part[wn][wm * 64 + mi * 16 + lg * 4 + r] = v;
    }
  __syncthreads();
  if (tid < 128)
    rmaxpart[(size_t)range * BB + m0 + tid] = fmaxf(part[0][tid], part[1][tid]);
}

// ==== reduce partial maxes -> per-row conservative f32 cutoff ====
__global__ __launch_bounds__(256) void k_rmax(const float* __restrict__ rmaxpart,
                                              float* __restrict__ cutF) {
  const int row = blockIdx.x * 256 + threadIdx.x;
  float m = -1e30f;
  for (int j = 0; j < NRG; ++j) m = fmaxf(m, rmaxpart[(size_t)j * BB + row]);
  const float t = m - 7.0f;
  cutF[row] = t - (fabsf(t) + 8.0f) * 0.00390625f - 1e-5f;  // safe f32 lower bound
}

// ==== pass 2: same mapping + staging; block-private segments; zero global atomics ====
__global__ __launch_bounds__(256) void k_simsB(const __hip_bfloat16* __restrict__ A,
                                               const __hip_bfloat16* __restrict__ Bm,
                                               const float* __restrict__ ck2,
                                               const float* __restrict__ cutF,
                                               unsigned long long* __restrict__ cand,
                                               int* __restrict__ cnt2) {
  __shared__ __hip_bfloat16 Bs[128 * 128];   // linear 32 KB, content XOR-swizzled per row
  __shared__ float cut_s[128];
  __shared__ int lcnt[128];
  const int tid = threadIdx.x;
  const int bid = blockIdx.x;
  const int gq = bid >> 6, rt = (bid >> 3) & 7, xq = bid & 7;
  const int range = gq * 8 + xq;
  if (range >= NRG) return;
  const int m0 = rt * 128;
  if (tid < 128) { cut_s[tid] = cutF[m0 + tid]; lcnt[tid] = 0; }
  const int l = tid & 63, w = tid >> 6;
  const int wm = w >> 1, wn = w & 1;
  const int lr = l & 15, lg = l >> 4;
  bf16x8 a[4][4];
#pragma unroll
  for (int mi = 0; mi < 4; ++mi) {
    const __hip_bfloat16* ar = A + (size_t)(m0 + wm * 64 + mi * 16 + lr) * DD + lg * 8;
#pragma unroll
    for (int kk = 0; kk < 4; ++kk) a[mi][kk] = *(const bf16x8*)(ar + kk * 32);
  }
  for (int i = 0; i < CTR; ++i) {
    const int ct = range * CTR + i;
    if (ct >= NCT) break;
    const int n0 = ct * 128;
    {
      const char* gbase = (const char*)(Bm + (size_t)n0 * DD);
#pragma unroll
      for (int j = 0; j < 8; ++j) {
        const int r = w * 32 + j * 4 + (l >> 4);
        const int b = ((l & 15) * 16) ^ ((r & 7) << 4);
        gload16(gbase + (size_t)r * 256 + b, (char*)Bs + w * 8192 + j * 1024);
      }
    }
    float c2l[4];
#pragma unroll
    for (int ni = 0; ni < 4; ++ni) c2l[ni] = 0.5f * ck2[n0 + wn * 64 + ni * 16 + lr];
    __syncthreads();
    f32x4 acc[4][4] = {};
#pragma unroll
    for (int kk = 0; kk < 4; ++kk) {
      bf16x8 b[4];
#pragma unroll
      for (int ni = 0; ni < 4; ++ni) {
        const int row = wn * 64 + ni * 16 + lr;
        const int boff = (kk * 64 + lg * 16) ^ ((row & 7) << 4);
        b[ni] = *(const bf16x8*)((const char*)Bs + row * 256 + boff);
      }
#pragma unroll
      for (int mi = 0; mi < 4; ++mi)
#pragma unroll
        for (int ni = 0; ni < 4; ++ni)
          acc[mi][ni] = __builtin_amdgcn_mfma_f32_16x16x32_bf16(a[mi][kk], b[ni], acc[mi][ni], 0, 0, 0);
    }
#pragma unroll
    for (int ni = 0; ni < 4; ++ni) {
      const int gcol = n0 + wn * 64 + ni * 16 + lr;
#pragma unroll
      for (int mi = 0; mi < 4; ++mi)
#pragma unroll
        for (int r = 0; r < 4; ++r) {
          const int lrow = wm * 64 + mi * 16 + lg * 4 + r;
          const float x = acc[mi][ni][r] - c2l[ni];
          if (x >= cut_s[lrow]) {
            const float v = __bfloat162float(__float2bfloat16(x));
            const int q = atomicAdd(&lcnt[lrow], 1);    // block-local LDS atomic
            if (q < SCAP2)
              cand[(size_t)(m0 + lrow) * CROW + range * SCAP2 + q] = mkkey(v, gcol);
          }
        }
    }
    __syncthreads();
  }
  if (tid < 128) {
    const int n = lcnt[tid];
    cnt2[(size_t)range * BB + m0 + tid] = n < SCAP2 ? n : SCAP2;
  }
}

// ===== select: compact 196 segments, then exact top-96 via bitwise binary-search =====
__global__ __launch_bounds__(256) void k_sortB(const unsigned long long* __restrict__ cand,
                                               const int* __restrict__ cnt2,
                                               int* __restrict__ idx_out) {
  __shared__ unsigned long long keys[CROW];  // 50.2 KB
  __shared__ int csum[NRG + 1];
  __shared__ int wred[40][4];
  __shared__ int outl[128];
  __shared__ int outc_sh;
  const int tid = threadIdx.x;
  const int wid = tid >> 6, lane = tid & 63;
  const int row = blockIdx.x;
  if (tid < NRG) csum[tid] = cnt2[(size_t)tid * BB + row];
  __syncthreads();
  if (tid == 0) {
    int s = 0;
    for (int j = 0; j < NRG; ++j) { const int c = csum[j]; csum[j] = s; s += c; }
    csum[NRG] = s;
  }
  __syncthreads();
  const int n = csum[NRG];
  if (tid < NRG) {
    const int base = csum[tid], c = csum[tid + 1] - base;
    const unsigned long long* src = cand + (size_t)row * CROW + tid * SCAP2;
    for (int j = 0; j < c; ++j) keys[base + j] = src[j];
  }
  __syncthreads();

  unsigned v16l[SREG];
  int idl[SREG];
#pragma unroll
  for (int s = 0; s < SREG; ++s) {
    const int i = tid + s * 256;
    if (i < n) {
      const unsigned long long k = keys[i];
      v16l[s] = (~(unsigned)(k >> 32)) >> 16;
      idl[s] = (int)(k & 0xFFFFFFFFu);
    } else {
      v16l[s] = 0u;
      idl[s] = 0x7FFFFFFF;
    }
  }

  int pass = 0;
  unsigned prefix = 0;
  int need = CS;
#pragma unroll
  for (int b = 15; b >= 0; --b) {
    int c1 = 0;
#pragma unroll
    for (int s = 0; s < SREG; ++s)
      c1 += ((v16l[s] >> (b + 1)) == prefix && ((v16l[s] >> b) & 1u)) ? 1 : 0;
#pragma unroll
    for (int d = 1; d < 64; d <<= 1) c1 += __shfl_xor(c1, d);
    if (lane == 0) wred[pass][wid] = c1;
    __syncthreads();
    const int cnt1 = wred[pass][0] + wred[pass][1] + wred[pass][2] + wred[pass][3];
    ++pass;
    if (need <= cnt1) prefix = (prefix << 1) | 1u;
    else { need -= cnt1; prefix = (prefix << 1); }
  }
  const unsigned V16star = prefix;

  unsigned iprefix = 0;
  int ineed = need;
#pragma unroll
  for (int b = 17; b >= 0; --b) {
    int c0 = 0;
#pragma unroll
    for (int s = 0; s < SREG; ++s)
      c0 += (v16l[s] == V16star && ((unsigned)idl[s] >> (b + 1)) == iprefix &&
             !(((unsigned)idl[s] >> b) & 1u)) ? 1 : 0;
#pragma unroll
    for (int d = 1; d < 64; d <<= 1) c0 += __shfl_xor(c0, d);
    if (lane == 0) wred[pass][wid] = c0;
    __syncthreads();
    const int cnt0 = wred[pass][0] + wred[pass][1] + wred[pass][2] + wred[pass][3];
    ++pass;
    if (ineed <= cnt0) iprefix = (iprefix << 1);
    else { ineed -= cnt0; iprefix = (iprefix << 1) | 1u; }
  }
  const unsigned ITstar = iprefix;

  if (tid == 0) outc_sh = 0;
  __syncthreads();
#pragma unroll
  for (int s = 0; s < SREG; ++s) {
    if (v16l[s] > V16star || (v16l[s] == V16star && (unsigned)idl[s] <= ITstar)) {
      const int q = atomicAdd(&outc_sh, 1);
      if (q < 128) outl[q] = idl[s];
    }
  }
  __syncthreads();
  const int ne = outc_sh;
  for (int i = tid; i < 128; i += 256)
    if (i >= ne) outl[i] = 0x7FFFFFFF;
  __syncthreads();
  for (int k = 2; k <= 128; k <<= 1) {
    for (int j = k >> 1; j > 0; j >>= 1) {
      if (tid < 128) {
        const int i = tid, ixj = i ^ j;
        if (ixj > i) {
          int a = outl[i], b = outl[ixj];
          const bool up = ((i & k) == 0);
          if ((a > b) == up) { outl[i] = b; outl[ixj] = a; }
        }
      }
      __syncthreads();
    }
  }
  if (tid < CS) {
    int id = outl[tid];
    if ((unsigned)id >= NC) id = 0;
    idx_out[row * CS + tid] = id;
  }
}

// ======== gather + context (MFMA T-MLP) + prediction head ========
#define LDB 136
__global__ __launch_bounds__(256) void k_final(const float* __restrict__ XH,
                                               const float* __restrict__ XK,
                                               const float* __restrict__ CK,
                                               const float* __restrict__ CY,
                                               const int* __restrict__ IDX,
                                               const __hip_bfloat16* __restrict__ Tw1t,
                                               const float* __restrict__ Tb1,
                                               const float* __restrict__ Tw2,
                                               const float* __restrict__ labw,
                                               const float* __restrict__ labb,
                                               const float* __restrict__ pg,
                                               const float* __restrict__ pb,
                                               const float* __restrict__ pw1,
                                               const float* __restrict__ pb1,
                                               const float* __restrict__ pw2,
                                               const float* __restrict__ pb2,
                                               const float* __restrict__ hg,
                                               const float* __restrict__ hb,
                                               const float* __restrict__ hw,
                                               const float* __restrict__ hbias,
                                               float* __restrict__ OUT) {
  __shared__ float diffs[CS * 132];
  __shared__ int ids[CS];
  __shared__ float yv[CS], simc[CS], pr[CS];
  __shared__ float kv[DD], xv[DD];
  __shared__ float qs[DBH];
  __shared__ float xrow[DD], hln[DD], t2[DBH], x2[DD];
  __shared__ float red[DD];
  __shared__ float smv[1];
  const int tid = threadIdx.x;
  const int b = blockIdx.x;
  if (tid < CS) ids[tid] = IDX[b * CS + tid];
  if (tid < DD) { kv[tid] = XK[(size_t)b * DD + tid]; xv[tid] = XH[(size_t)b * DD + tid]; }
  __syncthreads();
  if (tid < CS) yv[tid] = CY[ids[tid]];
  for (int e = tid; e < CS * DD; e += 256) {
    const int c = e >> 7, j = e & 127;
    diffs[c * 132 + j] = kv[j] - CK[(size_t)ids[c] * DD + j];
  }
  __syncthreads();
  if (tid < CS) {
    float s = 0.f;
    for (int j = 0; j < DD; ++j) { float d = diffs[tid * 132 + j]; s -= d * d; }
    simc[tid] = s;
  }
  __syncthreads();
  if (tid < DD) red[tid] = (tid < CS) ? simc[tid] : -1e30f;
  __syncthreads();
  for (int s = 64; s > 0; s >>= 1) { if (tid < s) red[tid] = fmaxf(red[tid], red[tid + s]); __syncthreads(); }
  const float mx = red[0];
  __syncthreads();
  if (tid < DD) red[tid] = (tid < CS) ? expf(simc[tid] - mx) : 0.f;
  if (tid < CS) pr[tid] = expf(simc[tid] - mx);
  __syncthreads();
  for (int s = 64; s > 0; s >>= 1) { if (tid < s) red[tid] += red[tid + s]; __syncthreads(); }
  const float inv = 1.f / red[0];
  __syncthreads();
  if (tid < CS) pr[tid] *= inv;
  if (tid < DD) red[tid] = (tid < CS) ? pr[tid] * yv[tid] : 0.f;
  __syncthreads();
  for (int s = 64; s > 0; s >>= 1) { if (tid < s) red[tid] += red[tid + s]; __syncthreads(); }
  if (tid == 0) smv[0] = red[0];
  __hip_bfloat16* db16 = (__hip_bfloat16*)diffs;
  {
    float4 f0s[6], f1s[6];
#pragma unroll
    for (int i = 0; i < 6; ++i) {
      const int gidx = tid + 256 * i;
      const int row = gidx >> 4, c8 = gidx & 15;
      f0s[i] = *(const float4*)(diffs + row * 132 + c8 * 8);
      f1s[i] = *(const float4*)(diffs + row * 132 + c8 * 8 + 4);
    }
    __syncthreads();
#pragma unroll
    for (int i = 0; i < 6; ++i) {
      const int gidx = tid + 256 * i;
      const int row = gidx >> 4, c8 = gidx & 15;
      *(uint4*)(db16 + row * LDB + c8 * 8) = pack8(f0s[i], f1s[i]);
    }
  }
  __syncthreads();
  {
    const int w = tid >> 6, l = tid & 63;
    const int lr = l & 15, lg = l >> 4;
    const int u0 = w * 64;
    bf16x8 af[6][4];
#pragma unroll
    for (int mt = 0; mt < 6; ++mt)
#pragma unroll
      for (int k = 0; k < 4; ++k)
        af[mt][k] = *(const bf16x8*)(db16 + (mt * 16 + lr) * LDB + k * 32 + lg * 8);
#pragma unroll
    for (int nt = 0; nt < 4; ++nt) {
      const int u = u0 + nt * 16 + lr;
      bf16x8 bfr[4];
#pragma unroll
      for (int k = 0; k < 4; ++k)
        bfr[k] = *(const bf16x8*)(Tw1t + (size_t)u * DD + k * 32 + lg * 8);
      const float bb = Tb1[u];
      float qacc = 0.f;
#pragma unroll
      for (int mt = 0; mt < 6; ++mt) {
        f32x4 acc = {};
#pragma unroll
        for (int k = 0; k < 4; ++k)
          acc = __builtin_amdgcn_mfma_f32_16x16x32_bf16(af[mt][k], bfr[k], acc, 0, 0, 0);
#pragma unroll
        for (int r = 0; r < 4; ++r) {
          const int c = mt * 16 + lg * 4 + r;
          qacc += pr[c] * fmaxf(acc[r] + bb, 0.f);
        }
      }
      qacc += __shfl_xor(qacc, 16);
      qacc += __shfl_xor(qacc, 32);
      if (lg == 0) qs[u] = qacc;
    }
  }
  __syncthreads();
  if (tid < DD) {
    const int d = tid;
    float cx = smv[0] * labw[d] + labb[d];
    for (int u4 = 0; u4 < 64; ++u4) {
      float4 q4 = *(const float4*)(&qs[u4 * 4]);
      cx += q4.x * Tw2[(u4 * 4 + 0) * DD + d];
      cx += q4.y * Tw2[(u4 * 4 + 1) * DD + d];
      cx += q4.z * Tw2[(u4 * 4 + 2) * DD + d];
      cx += q4.w * Tw2[(u4 * 4 + 3) * DD + d];
    }
    xrow[d] = xv[d] + cx;
  }
  __syncthreads();
  if (tid < DD) red[tid] = xrow[tid];
  __syncthreads();
  for (int s = 64; s > 0; s >>= 1) { if (tid < s) red[tid] += red[tid + s]; __syncthreads(); }
  const float m1 = red[0] * (1.f / 128.f);
  __syncthreads();
  if (tid < DD) { float d = xrow[tid] - m1; red[tid] = d * d; }
  __syncthreads();
  for (int s = 64; s > 0; s >>= 1) { if (tid < s) red[tid] += red[tid + s]; __syncthreads(); }
  const float rstd1 = 1.f / sqrtf(red[0] * (1.f / 128.f) + 1e-5f);
  __syncthreads();
  if (tid < DD) hln[tid] = (xrow[tid] - m1) * rstd1 * pg[tid] + pb[tid];
  __syncthreads();
  {
    const int u = tid;
    float s = pb1[u];
    for (int j4 = 0; j4 < 32; ++j4) {
      float4 h4 = *(const float4*)(hln + j4 * 4);
      s += h4.x * pw1[(j4 * 4 + 0) * DBH + u];
      s += h4.y * pw1[(j4 * 4 + 1) * DBH + u];
      s += h4.z * pw1[(j4 * 4 + 2) * DBH + u];
      s += h4.w * pw1[(j4 * 4 + 3) * DBH + u];
    }
    t2[u] = fmaxf(s, 0.f);
  }
  __syncthreads();
  if (tid < DD) {
    const int d = tid;
    float s = pb2[d];
    for (int u4 = 0; u4 < 64; ++u4) {
      float4 t4 = *(const float4*)(t2 + u4 * 4);
      s += t4.x * pw2[(u4 * 4 + 0) * DD + d];
      s += t4.y * pw2[(u4 * 4 + 1) * DD + d];
      s += t4.z * pw2[(u4 * 4 + 2) * DD + d];
      s += t4.w * pw2[(u4 * 4 + 3) * DD + d];
    }
    x2[d] = xrow[d] + s;
  }
  __syncthreads();
  if (tid < DD) red[tid] = x2[tid];
  __syncthreads();
  for (int s = 64; s > 0; s >>= 1) { if (tid < s) red[tid] += red[tid + s]; __syncthreads(); }
  const float m2 = red[0] * (1.f / 128.f);
  __syncthreads();
  if (tid < DD) { float d = x2[tid] - m2; red[tid] = d * d; }
  __syncthreads();
  for (int s = 64; s > 0; s >>= 1) { if (tid < s) red[tid] += red[tid + s]; __syncthreads(); }
  const float rstd2 = 1.f / sqrtf(red[0] * (1.f / 128.f) + 1e-5f);
  __syncthreads();
  if (tid < DD) {
    float z = (x2[tid] - m2) * rstd2 * hg[tid] + hb[tid];
    z = fmaxf(z, 0.f);
    red[tid] = z * hw[tid];
  }
  __syncthreads();
  for (int s = 64; s > 0; s >>= 1) { if (tid < s) red[tid] += red[tid + s]; __syncthreads(); }
  if (tid == 0) OUT[b] = red[0] + hbias[0];
}

// ======================================= launcher =======================================
extern "C" void kernel_launch(void* const* d_in, const int* in_sizes, int n_in,
                              void* d_out, int out_size, void* d_ws, size_t ws_size,
                              hipStream_t stream) {
  (void)in_sizes; (void)n_in; (void)out_size; (void)ws_size;
  const float* x_num      = (const float*)d_in[0];
  const float* cand_x     = (const float*)d_in[1];
  const float* cand_y     = (const float*)d_in[2];
  const float* W_in       = (const float*)d_in[3];
  const float* b_in       = (const float*)d_in[4];
  const float* enc_w1     = (const float*)d_in[5];
  const float* enc_b1     = (const float*)d_in[6];
  const float* enc_w2     = (const float*)d_in[7];
  const float* enc_b2     = (const float*)d_in[8];
  const float* ln_mix_g   = (const float*)d_in[9];
  const float* ln_mix_b   = (const float*)d_in[10];
  const float* K_w        = (const float*)d_in[11];
  const float* K_b        = (const float*)d_in[12];
  const float* lab_w      = (const float*)d_in[13];
  const float* lab_b      = (const float*)d_in[14];
  const float* T_w1       = (const float*)d_in[15];
  const float* T_b1       = (const float*)d_in[16];
  const float* T_w2       = (const float*)d_in[17];
  const float* pred_ln_g  = (const float*)d_in[18];
  const float* pred_ln_b  = (const float*)d_in[19];
  const float* pred_w1    = (const float*)d_in[20];
  const float* pred_b1    = (const float*)d_in[21];
  const float* pred_w2    = (const float*)d_in[22];
  const float* pred_b2    = (const float*)d_in[23];
  const float* head_ln_g  = (const float*)d_in[24];
  const float* head_ln_b  = (const float*)d_in[25];
  const float* head_w     = (const float*)d_in[26];
  const float* head_b     = (const float*)d_in[27];
  float* out = (float*)d_out;

  char* w8 = (char*)d_ws;
  size_t off = 0;
  float* cand_k = (float*)(w8 + off);              off += (size_t)NC * DD * 4;
  float* cand_ck2 = (float*)(w8 + off);            off += (size_t)NCP * 4 + 256;
  float* xh = (float*)(w8 + off);                  off += (size_t)BB * DD * 4;
  float* xk = (float*)(w8 + off);                  off += (size_t)BB * DD * 4;
  float* xk2 = (float*)(w8 + off);                 off += 4096;
  __hip_bfloat16* xkb16 = (__hip_bfloat16*)(w8 + off); off += (size_t)BB * DD * 2;
  int* idx_all = (int*)(w8 + off);                 off += (size_t)BB * CS * 4;
  __hip_bfloat16* w1t = (__hip_bfloat16*)(w8 + off); off += (size_t)DBH * DD * 2;
  __hip_bfloat16* w2t = (__hip_bfloat16*)(w8 + off); off += (size_t)DD * DBH * 2;
  __hip_bfloat16* kwt = (__hip_bfloat16*)(w8 + off); off += (size_t)DD * DD * 2;
  __hip_bfloat16* tw1t = (__hip_bfloat16*)(w8 + off); off += (size_t)DBH * DD * 2;
  char* big = w8 + off;
  // overlay in `big`: candb [1024][CROW] u64 (51.4 MB) at 0; rmaxpart/cnt2/cutF at +56 MB;
  // ckb16 [NCP,128] bf16 at +102.4 MB
  unsigned long long* candb = (unsigned long long*)big;
  float* rmaxpart = (float*)(big + (size_t)56 * 1024 * 1024);            // 803 KB
  int* cnt2 = (int*)(big + (size_t)57 * 1024 * 1024);                    // 803 KB
  float* cutF = (float*)(big + (size_t)58 * 1024 * 1024);                // 4 KB
  __hip_bfloat16* ckb16 = (__hip_bfloat16*)(big + (size_t)NC * DD * 4);

  k_prep<<<128, 256, 0, stream>>>(enc_w1, enc_w2, K_w, T_w1, w1t, w2t, kwt, tw1t);
  k_pad<<<32, 256, 0, stream>>>(ckb16, cand_ck2);
  // ---- fused encoder: candidates then queries ----
  k_encf<<<NC / 64, 256, 0, stream>>>(cand_x, W_in, b_in, w1t, enc_b1, w2t, enc_b2,
                                      ln_mix_g, ln_mix_b, kwt, K_b,
                                      cand_k, ckb16, cand_ck2, nullptr);
  k_encf<<<BB / 64, 256, 0, stream>>>(x_num, W_in, b_in, w1t, enc_b1, w2t, enc_b2,
                                      ln_mix_g, ln_mix_b, kwt, K_b,
                                      xk, xkb16, xk2, xh);
  // ---- scores + top-96: atomic-free two-pass, XCD-affine, async B staging ----
  k_simsA<<<1600, 256, 0, stream>>>(xkb16, ckb16, cand_ck2, rmaxpart);
  k_rmax<<<4, 256, 0, stream>>>(rmaxpart, cutF);
  k_simsB<<<1600, 256, 0, stream>>>(xkb16, ckb16, cand_ck2, cutF, candb, cnt2);
  k_sortB<<<BB, 256, 0, stream>>>(candb, cnt2, idx_all);
  // ---- gather + context + head ----
  k_final<<<BB, 256, 0, stream>>>(xh, xk, cand_k, cand_y, idx_all,
                                  tw1t, T_b1, T_w2, lab_w, lab_b,
                                  pred_ln_g, pred_ln_b, pred_w1, pred_b1, pred_w2, pred_b2,
                                  head_ln_g, head_ln_b, head_w, head_b, out);
}

// Round 18
// 582.197 us; speedup vs baseline: 1.1634x; 1.1634x over previous
//
#include <hip/hip_runtime.h>
#include <hip/hip_bf16.h>

#define NC 200000
#define NCP 200064
#define NCT 1563
#define NRG 196
#define CTR 8
#define SCAP2 32
#define CROW (NRG * SCAP2)   // 6272 slots per row
#define SREG 25              // ceil(6272/256)
#define BB 1024
#define DD 128
#define DBH 256
#define CS 96

typedef __attribute__((ext_vector_type(8))) short bf16x8;
typedef __attribute__((ext_vector_type(4))) float f32x4;

#define LDH 136
#define LDU 264

__device__ inline uint4 pack8(const float4 a, const float4 b) {
  union { __hip_bfloat16 h[8]; uint4 v; } r;
  r.h[0] = __float2bfloat16(a.x); r.h[1] = __float2bfloat16(a.y);
  r.h[2] = __float2bfloat16(a.z); r.h[3] = __float2bfloat16(a.w);
  r.h[4] = __float2bfloat16(b.x); r.h[5] = __float2bfloat16(b.y);
  r.h[6] = __float2bfloat16(b.z); r.h[7] = __float2bfloat16(b.w);
  return r.v;
}

__device__ inline unsigned encf(float v) {
  unsigned b = __float_as_uint(v);
  return (b & 0x80000000u) ? ~b : (b | 0x80000000u);
}
__device__ inline float decf(unsigned u) {
  return __uint_as_float((u & 0x80000000u) ? (u ^ 0x80000000u) : ~u);
}
// key: high32 = ~enc(v)  (u64-ascending == value-descending), low32 = idx
__device__ inline unsigned long long mkkey(float v, int idx) {
  unsigned u = encf(v);
  return (((unsigned long long)(~u)) << 32) | (unsigned)idx;
}

// async 16B global -> LDS (wave-uniform LDS base + lane*16)
__device__ inline void gload16(const void* g, void* l) {
  __builtin_amdgcn_global_load_lds((const __attribute__((address_space(1))) void*)g,
                                   (__attribute__((address_space(3))) void*)l, 16, 0, 0);
}

// ====================== weight prep: bf16 transposed copies ======================
__global__ __launch_bounds__(256) void k_prep(const float* __restrict__ w1,
                                              const float* __restrict__ w2,
                                              const float* __restrict__ kw,
                                              const float* __restrict__ tw1,
                                              __hip_bfloat16* __restrict__ w1t,
                                              __hip_bfloat16* __restrict__ w2t,
                                              __hip_bfloat16* __restrict__ kwt,
                                              __hip_bfloat16* __restrict__ tw1t) {
  const int i = blockIdx.x * 256 + threadIdx.x;
  if (i < 32768) {
    const int u = i >> 7, j = i & 127;
    w1t[i] = __float2bfloat16(w1[j * DBH + u]);
    tw1t[i] = __float2bfloat16(tw1[j * DBH + u]);
  }
  if (i < 32768) {
    const int d = i >> 8, u = i & 255;
    w2t[i] = __float2bfloat16(w2[u * DD + d]);
  }
  if (i < 16384) {
    const int d = i >> 7, j = i & 127;
    kwt[i] = __float2bfloat16(kw[j * DD + d]);
  }
}

// ================= pad rows [NC, NCP): zero keys, huge ck2 (scores ~ -5e8) =================
__global__ __launch_bounds__(256) void k_pad(__hip_bfloat16* __restrict__ ckb16,
                                             float* __restrict__ ck2) {
  const int i = blockIdx.x * 256 + threadIdx.x;
  if (i < (NCP - NC) * DD) ckb16[(size_t)NC * DD + i] = __float2bfloat16(0.f);
  if (i < (NCP - NC)) ck2[NC + i] = 1e9f;
}

// ============================ encoder stage 1: H = X @ W_in + b ============================
__global__ __launch_bounds__(256) void k_e1(const float* __restrict__ X,
                                            const float* __restrict__ W,
                                            const float* __restrict__ bias,
                                            float* __restrict__ H) {
  __shared__ float Xs[32 * 32];
  const int tid = threadIdx.x;
  const int r0 = blockIdx.x * 32;
  ((float4*)Xs)[tid] = ((const float4*)(X + (size_t)r0 * 32))[tid];
  __syncthreads();
  const int d0 = tid & 63;
  const int rh = tid >> 6;
  float acc0[8], acc1[8];
  const float b0 = bias[d0], b1 = bias[d0 + 64];
#pragma unroll
  for (int r = 0; r < 8; ++r) { acc0[r] = b0; acc1[r] = b1; }
#pragma unroll
  for (int k4 = 0; k4 < 8; ++k4) {
    float w0[4], w1[4];
#pragma unroll
    for (int kk = 0; kk < 4; ++kk) {
      w0[kk] = W[(k4 * 4 + kk) * DD + d0];
      w1[kk] = W[(k4 * 4 + kk) * DD + d0 + 64];
    }
#pragma unroll
    for (int r = 0; r < 8; ++r) {
      float4 x4 = ((const float4*)(Xs + (rh * 8 + r) * 32))[k4];
      acc0[r] += x4.x * w0[0] + x4.y * w0[1] + x4.z * w0[2] + x4.w * w0[3];
      acc1[r] += x4.x * w1[0] + x4.y * w1[1] + x4.z * w1[2] + x4.w * w1[3];
    }
  }
#pragma unroll
  for (int r = 0; r < 8; ++r) {
    const size_t row = (size_t)(r0 + rh * 8 + r);
    H[row * DD + d0] = acc0[r];
    H[row * DD + d0 + 64] = acc1[r];
  }
}

// ============== encoder stage 2+3 (MFMA): H = H + relu(H@W1 + b1)@W2 + b2 ==============
__global__ __launch_bounds__(256) void k_e23m(float* __restrict__ H,
                                              const __hip_bfloat16* __restrict__ W1t,
                                              const float* __restrict__ B1,
                                              const __hip_bfloat16* __restrict__ W2t,
                                              const float* __restrict__ B2) {
  __shared__ __hip_bfloat16 Hs[64 * LDH];
  __shared__ __hip_bfloat16 Us[64 * LDU];
  const int tid = threadIdx.x;
  const int r0 = blockIdx.x * 64;
#pragma unroll
  for (int i = 0; i < 4; ++i) {
    const int e8 = i * 256 + tid;
    const int row = e8 >> 4, c8 = e8 & 15;
    const float* src = H + (size_t)(r0 + row) * DD + c8 * 8;
    float4 f0 = *(const float4*)(src);
    float4 f1 = *(const float4*)(src + 4);
    *(uint4*)(Hs + row * LDH + c8 * 8) = pack8(f0, f1);
  }
  __syncthreads();
  const int l = tid & 63, w = tid >> 6;
  const int lr = l & 15, lg = l >> 4;
  {  // phase 1: U = relu(H @ W1 + b1)
    f32x4 acc[4][4] = {};
#pragma unroll
    for (int kk = 0; kk < 4; ++kk) {
      bf16x8 a[4], b[4];
#pragma unroll
      for (int mi = 0; mi < 4; ++mi)
        a[mi] = *(const bf16x8*)(Hs + (mi * 16 + lr) * LDH + kk * 32 + lg * 8);
#pragma unroll
      for (int ni = 0; ni < 4; ++ni)
        b[ni] = *(const bf16x8*)(W1t + (size_t)(w * 64 + ni * 16 + lr) * DD + kk * 32 + lg * 8);
#pragma unroll
      for (int mi = 0; mi < 4; ++mi)
#pragma unroll
        for (int ni = 0; ni < 4; ++ni)
          acc[mi][ni] = __builtin_amdgcn_mfma_f32_16x16x32_bf16(a[mi], b[ni], acc[mi][ni], 0, 0, 0);
    }
#pragma unroll
    for (int ni = 0; ni < 4; ++ni) {
      const int col = w * 64 + ni * 16 + lr;
      const float bb = B1[col];
#pragma unroll
      for (int mi = 0; mi < 4; ++mi)
#pragma unroll
        for (int r = 0; r < 4; ++r) {
          const int row = mi * 16 + lg * 4 + r;
          Us[row * LDU + col] = __float2bfloat16(fmaxf(acc[mi][ni][r] + bb, 0.f));
        }
    }
  }
  __syncthreads();
  {  // phase 2: H += U @ W2 + b2
    f32x4 acc[4][2] = {};
#pragma unroll
    for (int kk = 0; kk < 8; ++kk) {
      bf16x8 a[4], b[2];
#pragma unroll
      for (int mi = 0; mi < 4; ++mi)
        a[mi] = *(const bf16x8*)(Us + (mi * 16 + lr) * LDU + kk * 32 + lg * 8);
#pragma unroll
      for (int ni = 0; ni < 2; ++ni)
        b[ni] = *(const bf16x8*)(W2t + (size_t)(w * 32 + ni * 16 + lr) * DBH + kk * 32 + lg * 8);
#pragma unroll
      for (int mi = 0; mi < 4; ++mi)
#pragma unroll
        for (int ni = 0; ni < 2; ++ni)
          acc[mi][ni] = __builtin_amdgcn_mfma_f32_16x16x32_bf16(a[mi], b[ni], acc[mi][ni], 0, 0, 0);
    }
#pragma unroll
    for (int ni = 0; ni < 2; ++ni) {
      const int col = w * 32 + ni * 16 + lr;
      const float bb = B2[col];
#pragma unroll
      for (int mi = 0; mi < 4; ++mi)
#pragma unroll
        for (int r = 0; r < 4; ++r) {
          const int row = mi * 16 + lg * 4 + r;
          const size_t g = (size_t)(r0 + row) * DD + col;
          H[g] = H[g] + acc[mi][ni][r] + bb;
        }
    }
  }
}

// ====== encoder stage 4 (MFMA): K = LN(H)@Kw + Kb ; bf16 copy + rowwise sum(K^2) ======
__global__ __launch_bounds__(256) void k_e4m(const float* __restrict__ H,
                                             const float* __restrict__ g,
                                             const float* __restrict__ bln,
                                             const __hip_bfloat16* __restrict__ Kwt,
                                             const float* __restrict__ Kb,
                                             float* __restrict__ Kout,
                                             __hip_bfloat16* __restrict__ Kb16,
                                             float* __restrict__ k2out) {
  __shared__ __hip_bfloat16 Ls[64 * LDH];
  __shared__ float k2s[64];
  const int tid = threadIdx.x;
  const int r0 = blockIdx.x * 64;
  if (tid < 64) k2s[tid] = 0.f;
  {
    const int row = tid >> 2, q = tid & 3;
    const float* hr = H + (size_t)(r0 + row) * DD + q * 32;
    float v[32];
#pragma unroll
    for (int i = 0; i < 8; ++i) {
      float4 f = ((const float4*)hr)[i];
      v[i * 4 + 0] = f.x; v[i * 4 + 1] = f.y; v[i * 4 + 2] = f.z; v[i * 4 + 3] = f.w;
    }
    float s = 0.f;
#pragma unroll
    for (int i = 0; i < 32; ++i) s += v[i];
    s += __shfl_xor(s, 1); s += __shfl_xor(s, 2);
    const float mean = s * (1.f / 128.f);
    float vs = 0.f;
#pragma unroll
    for (int i = 0; i < 32; ++i) { float d = v[i] - mean; vs += d * d; }
    vs += __shfl_xor(vs, 1); vs += __shfl_xor(vs, 2);
    const float rstd = 1.f / sqrtf(vs * (1.f / 128.f) + 1e-5f);
#pragma unroll
    for (int i = 0; i < 4; ++i) {
      float t[8];
#pragma unroll
      for (int j = 0; j < 8; ++j) {
        const int col = q * 32 + i * 8 + j;
        t[j] = (v[i * 8 + j] - mean) * rstd * g[col] + bln[col];
      }
      float4 f0 = {t[0], t[1], t[2], t[3]}, f1 = {t[4], t[5], t[6], t[7]};
      *(uint4*)(Ls + row * LDH + q * 32 + i * 8) = pack8(f0, f1);
    }
  }
  __syncthreads();
  const int l = tid & 63, w = tid >> 6;
  const int lr = l & 15, lg = l >> 4;
  f32x4 acc[4][2] = {};
#pragma unroll
  for (int kk = 0; kk < 4; ++kk) {
    bf16x8 a[4], b[2];
#pragma unroll
    for (int mi = 0; mi < 4; ++mi)
      a[mi] = *(const bf16x8*)(Ls + (mi * 16 + lr) * LDH + kk * 32 + lg * 8);
#pragma unroll
    for (int ni = 0; ni < 2; ++ni)
      b[ni] = *(const bf16x8*)(Kwt + (size_t)(w * 32 + ni * 16 + lr) * DD + kk * 32 + lg * 8);
#pragma unroll
    for (int mi = 0; mi < 4; ++mi)
#pragma unroll
      for (int ni = 0; ni < 2; ++ni)
        acc[mi][ni] = __builtin_amdgcn_mfma_f32_16x16x32_bf16(a[mi], b[ni], acc[mi][ni], 0, 0, 0);
  }
  float p[4][4];
#pragma unroll
  for (int mi = 0; mi < 4; ++mi)
#pragma unroll
    for (int r = 0; r < 4; ++r) p[mi][r] = 0.f;
#pragma unroll
  for (int ni = 0; ni < 2; ++ni) {
    const int col = w * 32 + ni * 16 + lr;
    const float kb = Kb[col];
#pragma unroll
    for (int mi = 0; mi < 4; ++mi)
#pragma unroll
      for (int r = 0; r < 4; ++r) {
        const float val = acc[mi][ni][r] + kb;
        const int row = mi * 16 + lg * 4 + r;
        const size_t gg = (size_t)(r0 + row) * DD + col;
        Kout[gg] = val;
        Kb16[gg] = __float2bfloat16(val);
        p[mi][r] += val * val;
      }
  }
#pragma unroll
  for (int mi = 0; mi < 4; ++mi)
#pragma unroll
    for (int r = 0; r < 4; ++r) {
      float t = p[mi][r];
      t += __shfl_xor(t, 1); t += __shfl_xor(t, 2);
      t += __shfl_xor(t, 4); t += __shfl_xor(t, 8);
      if (lr == 0) atomicAdd(&k2s[mi * 16 + lg * 4 + r], t);
    }
  __syncthreads();
  if (tid < 64) k2out[r0 + tid] = k2s[tid];
}

// ==== pass 1: block=(rowtile, range); XCD-affine; B via global_load_lds + XOR swizzle ====
__global__ __launch_bounds__(256) void k_simsA(const __hip_bfloat16* __restrict__ A,
                                               const __hip_bfloat16* __restrict__ Bm,
                                               const float* __restrict__ ck2,
                                               float* __restrict__ rmaxpart) {
  __shared__ __hip_bfloat16 Bs[128 * 128];   // linear 32 KB, content XOR-swizzled per row
  __shared__ float part[2][128];
  const int tid = threadIdx.x;
  const int bid = blockIdx.x;         // grid 1600 = 25 x 8rt x 8x
  const int gq = bid >> 6, rt = (bid >> 3) & 7, xq = bid & 7;
  const int range = gq * 8 + xq;
  if (range >= NRG) return;
  const int m0 = rt * 128;
  const int l = tid & 63, w = tid >> 6;
  const int wm = w >> 1, wn = w & 1;
  const int lr = l & 15, lg = l >> 4;
  bf16x8 a[4][4];
#pragma unroll
  for (int mi = 0; mi < 4; ++mi) {
    const __hip_bfloat16* ar = A + (size_t)(m0 + wm * 64 + mi * 16 + lr) * DD + lg * 8;
#pragma unroll
    for (int kk = 0; kk < 4; ++kk) a[mi][kk] = *(const bf16x8*)(ar + kk * 32);
  }
  float vmax[4][4];
#pragma unroll
  for (int mi = 0; mi < 4; ++mi)
#pragma unroll
    for (int r = 0; r < 4; ++r) vmax[mi][r] = -1e30f;
  for (int i = 0; i < CTR; ++i) {
    const int ct = range * CTR + i;
    if (ct >= NCT) break;
    const int n0 = ct * 128;
    {  // async staged, source pre-swizzled so swizzled read is conflict-free
      const char* gbase = (const char*)(Bm + (size_t)n0 * DD);
#pragma unroll
      for (int j = 0; j < 8; ++j) {
        const int r = w * 32 + j * 4 + (l >> 4);
        const int b = ((l & 15) * 16) ^ ((r & 7) << 4);
        gload16(gbase + (size_t)r * 256 + b, (char*)Bs + w * 8192 + j * 1024);
      }
    }
    float c2l[4];
#pragma unroll
    for (int ni = 0; ni < 4; ++ni) c2l[ni] = 0.5f * ck2[n0 + wn * 64 + ni * 16 + lr];
    __syncthreads();
    f32x4 acc[4][4] = {};
#pragma unroll
    for (int kk = 0; kk < 4; ++kk) {
      bf16x8 b[4];
#pragma unroll
      for (int ni = 0; ni < 4; ++ni) {
        const int row = wn * 64 + ni * 16 + lr;
        const int boff = (kk * 64 + lg * 16) ^ ((row & 7) << 4);
        b[ni] = *(const bf16x8*)((const char*)Bs + row * 256 + boff);
      }
#pragma unroll
      for (int mi = 0; mi < 4; ++mi)
#pragma unroll
        for (int ni = 0; ni < 4; ++ni)
          acc[mi][ni] = __builtin_amdgcn_mfma_f32_16x16x32_bf16(a[mi][kk], b[ni], acc[mi][ni], 0, 0, 0);
    }
#pragma unroll
    for (int mi = 0; mi < 4; ++mi)
#pragma unroll
      for (int r = 0; r < 4; ++r)
#pragma unroll
        for (int ni = 0; ni < 4; ++ni)
          vmax[mi][r] = fmaxf(vmax[mi][r], acc[mi][ni][r] - c2l[ni]);
    __syncthreads();
  }
#pragma unroll
  for (int mi = 0; mi < 4; ++mi)
#pragma unroll
    for (int r = 0; r < 4; ++r) {
      float v = vmax[mi][r];
#pragma unroll
      for (int mk = 1; mk < 16; mk <<= 1) v = fmaxf(v, __shfl_xor(v, mk));
      if (lr == 0) part[wn][wm * 64 + mi * 16 + lg * 4 + r] = v;
    }
  __syncthreads();
  if (tid < 128)
    rmaxpart[(size_t)range * BB + m0 + tid] = fmaxf(part[0][tid], part[1][tid]);
}

// ==== reduce partial maxes -> per-row conservative f32 cutoff ====
__global__ __launch_bounds__(256) void k_rmax(const float* __restrict__ rmaxpart,
                                              float* __restrict__ cutF) {
  const int row = blockIdx.x * 256 + threadIdx.x;
  float m = -1e30f;
  for (int j = 0; j < NRG; ++j) m = fmaxf(m, rmaxpart[(size_t)j * BB + row]);
  const float t = m - 7.0f;
  cutF[row] = t - (fabsf(t) + 8.0f) * 0.00390625f - 1e-5f;  // safe f32 lower bound
}

// ==== pass 2: same mapping + staging; block-private segments; zero global atomics ====
__global__ __launch_bounds__(256) void k_simsB(const __hip_bfloat16* __restrict__ A,
                                               const __hip_bfloat16* __restrict__ Bm,
                                               const float* __restrict__ ck2,
                                               const float* __restrict__ cutF,
                                               unsigned long long* __restrict__ cand,
                                               int* __restrict__ cnt2) {
  __shared__ __hip_bfloat16 Bs[128 * 128];   // linear 32 KB, content XOR-swizzled per row
  __shared__ float cut_s[128];
  __shared__ int lcnt[128];
  const int tid = threadIdx.x;
  const int bid = blockIdx.x;
  const int gq = bid >> 6, rt = (bid >> 3) & 7, xq = bid & 7;
  const int range = gq * 8 + xq;
  if (range >= NRG) return;
  const int m0 = rt * 128;
  if (tid < 128) { cut_s[tid] = cutF[m0 + tid]; lcnt[tid] = 0; }
  const int l = tid & 63, w = tid >> 6;
  const int wm = w >> 1, wn = w & 1;
  const int lr = l & 15, lg = l >> 4;
  bf16x8 a[4][4];
#pragma unroll
  for (int mi = 0; mi < 4; ++mi) {
    const __hip_bfloat16* ar = A + (size_t)(m0 + wm * 64 + mi * 16 + lr) * DD + lg * 8;
#pragma unroll
    for (int kk = 0; kk < 4; ++kk) a[mi][kk] = *(const bf16x8*)(ar + kk * 32);
  }
  for (int i = 0; i < CTR; ++i) {
    const int ct = range * CTR + i;
    if (ct >= NCT) break;
    const int n0 = ct * 128;
    {
      const char* gbase = (const char*)(Bm + (size_t)n0 * DD);
#pragma unroll
      for (int j = 0; j < 8; ++j) {
        const int r = w * 32 + j * 4 + (l >> 4);
        const int b = ((l & 15) * 16) ^ ((r & 7) << 4);
        gload16(gbase + (size_t)r * 256 + b, (char*)Bs + w * 8192 + j * 1024);
      }
    }
    float c2l[4];
#pragma unroll
    for (int ni = 0; ni < 4; ++ni) c2l[ni] = 0.5f * ck2[n0 + wn * 64 + ni * 16 + lr];
    __syncthreads();
    f32x4 acc[4][4] = {};
#pragma unroll
    for (int kk = 0; kk < 4; ++kk) {
      bf16x8 b[4];
#pragma unroll
      for (int ni = 0; ni < 4; ++ni) {
        const int row = wn * 64 + ni * 16 + lr;
        const int boff = (kk * 64 + lg * 16) ^ ((row & 7) << 4);
        b[ni] = *(const bf16x8*)((const char*)Bs + row * 256 + boff);
      }
#pragma unroll
      for (int mi = 0; mi < 4; ++mi)
#pragma unroll
        for (int ni = 0; ni < 4; ++ni)
          acc[mi][ni] = __builtin_amdgcn_mfma_f32_16x16x32_bf16(a[mi][kk], b[ni], acc[mi][ni], 0, 0, 0);
    }
#pragma unroll
    for (int ni = 0; ni < 4; ++ni) {
      const int gcol = n0 + wn * 64 + ni * 16 + lr;
#pragma unroll
      for (int mi = 0; mi < 4; ++mi)
#pragma unroll
        for (int r = 0; r < 4; ++r) {
          const int lrow = wm * 64 + mi * 16 + lg * 4 + r;
          const float x = acc[mi][ni][r] - c2l[ni];
          if (x >= cut_s[lrow]) {
            const float v = __bfloat162float(__float2bfloat16(x));
            const int q = atomicAdd(&lcnt[lrow], 1);    // block-local LDS atomic
            if (q < SCAP2)
              cand[(size_t)(m0 + lrow) * CROW + range * SCAP2 + q] = mkkey(v, gcol);
          }
        }
    }
    __syncthreads();
  }
  if (tid < 128) {
    const int n = lcnt[tid];
    cnt2[(size_t)range * BB + m0 + tid] = n < SCAP2 ? n : SCAP2;
  }
}

// ===== select: compact 196 segments, then exact top-96 via bitwise binary-search =====
__global__ __launch_bounds__(256) void k_sortB(const unsigned long long* __restrict__ cand,
                                               const int* __restrict__ cnt2,
                                               int* __restrict__ idx_out) {
  __shared__ unsigned long long keys[CROW];  // 50.2 KB
  __shared__ int csum[NRG + 1];
  __shared__ int wred[40][4];
  __shared__ int outl[128];
  __shared__ int outc_sh;
  const int tid = threadIdx.x;
  const int wid = tid >> 6, lane = tid & 63;
  const int row = blockIdx.x;
  if (tid < NRG) csum[tid] = cnt2[(size_t)tid * BB + row];
  __syncthreads();
  if (tid == 0) {
    int s = 0;
    for (int j = 0; j < NRG; ++j) { const int c = csum[j]; csum[j] = s; s += c; }
    csum[NRG] = s;
  }
  __syncthreads();
  const int n = csum[NRG];
  if (tid < NRG) {
    const int base = csum[tid], c = csum[tid + 1] - base;
    const unsigned long long* src = cand + (size_t)row * CROW + tid * SCAP2;
    for (int j = 0; j < c; ++j) keys[base + j] = src[j];
  }
  __syncthreads();

  unsigned v16l[SREG];
  int idl[SREG];
#pragma unroll
  for (int s = 0; s < SREG; ++s) {
    const int i = tid + s * 256;
    if (i < n) {
      const unsigned long long k = keys[i];
      v16l[s] = (~(unsigned)(k >> 32)) >> 16;
      idl[s] = (int)(k & 0xFFFFFFFFu);
    } else {
      v16l[s] = 0u;
      idl[s] = 0x7FFFFFFF;
    }
  }

  int pass = 0;
  unsigned prefix = 0;
  int need = CS;
#pragma unroll
  for (int b = 15; b >= 0; --b) {
    int c1 = 0;
#pragma unroll
    for (int s = 0; s < SREG; ++s)
      c1 += ((v16l[s] >> (b + 1)) == prefix && ((v16l[s] >> b) & 1u)) ? 1 : 0;
#pragma unroll
    for (int d = 1; d < 64; d <<= 1) c1 += __shfl_xor(c1, d);
    if (lane == 0) wred[pass][wid] = c1;
    __syncthreads();
    const int cnt1 = wred[pass][0] + wred[pass][1] + wred[pass][2] + wred[pass][3];
    ++pass;
    if (need <= cnt1) prefix = (prefix << 1) | 1u;
    else { need -= cnt1; prefix = (prefix << 1); }
  }
  const unsigned V16star = prefix;

  unsigned iprefix = 0;
  int ineed = need;
#pragma unroll
  for (int b = 17; b >= 0; --b) {
    int c0 = 0;
#pragma unroll
    for (int s = 0; s < SREG; ++s)
      c0 += (v16l[s] == V16star && ((unsigned)idl[s] >> (b + 1)) == iprefix &&
             !(((unsigned)idl[s] >> b) & 1u)) ? 1 : 0;
#pragma unroll
    for (int d = 1; d < 64; d <<= 1) c0 += __shfl_xor(c0, d);
    if (lane == 0) wred[pass][wid] = c0;
    __syncthreads();
    const int cnt0 = wred[pass][0] + wred[pass][1] + wred[pass][2] + wred[pass][3];
    ++pass;
    if (ineed <= cnt0) iprefix = (iprefix << 1);
    else { ineed -= cnt0; iprefix = (iprefix << 1) | 1u; }
  }
  const unsigned ITstar = iprefix;

  if (tid == 0) outc_sh = 0;
  __syncthreads();
#pragma unroll
  for (int s = 0; s < SREG; ++s) {
    if (v16l[s] > V16star || (v16l[s] == V16star && (unsigned)idl[s] <= ITstar)) {
      const int q = atomicAdd(&outc_sh, 1);
      if (q < 128) outl[q] = idl[s];
    }
  }
  __syncthreads();
  const int ne = outc_sh;
  for (int i = tid; i < 128; i += 256)
    if (i >= ne) outl[i] = 0x7FFFFFFF;
  __syncthreads();
  for (int k = 2; k <= 128; k <<= 1) {
    for (int j = k >> 1; j > 0; j >>= 1) {
      if (tid < 128) {
        const int i = tid, ixj = i ^ j;
        if (ixj > i) {
          int a = outl[i], b = outl[ixj];
          const bool up = ((i & k) == 0);
          if ((a > b) == up) { outl[i] = b; outl[ixj] = a; }
        }
      }
      __syncthreads();
    }
  }
  if (tid < CS) {
    int id = outl[tid];
    if ((unsigned)id >= NC) id = 0;
    idx_out[row * CS + tid] = id;
  }
}

// ======== gather + context (MFMA T-MLP) + prediction head ========
#define LDB 136
__global__ __launch_bounds__(256) void k_final(const float* __restrict__ XH,
                                               const float* __restrict__ XK,
                                               const float* __restrict__ CK,
                                               const float* __restrict__ CY,
                                               const int* __restrict__ IDX,
                                               const __hip_bfloat16* __restrict__ Tw1t,
                                               const float* __restrict__ Tb1,
                                               const float* __restrict__ Tw2,
                                               const float* __restrict__ labw,
                                               const float* __restrict__ labb,
                                               const float* __restrict__ pg,
                                               const float* __restrict__ pb,
                                               const float* __restrict__ pw1,
                                               const float* __restrict__ pb1,
                                               const float* __restrict__ pw2,
                                               const float* __restrict__ pb2,
                                               const float* __restrict__ hg,
                                               const float* __restrict__ hb,
                                               const float* __restrict__ hw,
                                               const float* __restrict__ hbias,
                                               float* __restrict__ OUT) {
  __shared__ float diffs[CS * 132];
  __shared__ int ids[CS];
  __shared__ float yv[CS], simc[CS], pr[CS];
  __shared__ float kv[DD], xv[DD];
  __shared__ float qs[DBH];
  __shared__ float xrow[DD], hln[DD], t2[DBH], x2[DD];
  __shared__ float red[DD];
  __shared__ float smv[1];
  const int tid = threadIdx.x;
  const int b = blockIdx.x;
  if (tid < CS) ids[tid] = IDX[b * CS + tid];
  if (tid < DD) { kv[tid] = XK[(size_t)b * DD + tid]; xv[tid] = XH[(size_t)b * DD + tid]; }
  __syncthreads();
  if (tid < CS) yv[tid] = CY[ids[tid]];
  for (int e = tid; e < CS * DD; e += 256) {
    const int c = e >> 7, j = e & 127;
    diffs[c * 132 + j] = kv[j] - CK[(size_t)ids[c] * DD + j];
  }
  __syncthreads();
  if (tid < CS) {
    float s = 0.f;
    for (int j = 0; j < DD; ++j) { float d = diffs[tid * 132 + j]; s -= d * d; }
    simc[tid] = s;
  }
  __syncthreads();
  if (tid < DD) red[tid] = (tid < CS) ? simc[tid] : -1e30f;
  __syncthreads();
  for (int s = 64; s > 0; s >>= 1) { if (tid < s) red[tid] = fmaxf(red[tid], red[tid + s]); __syncthreads(); }
  const float mx = red[0];
  __syncthreads();
  if (tid < DD) red[tid] = (tid < CS) ? expf(simc[tid] - mx) : 0.f;
  if (tid < CS) pr[tid] = expf(simc[tid] - mx);
  __syncthreads();
  for (int s = 64; s > 0; s >>= 1) { if (tid < s) red[tid] += red[tid + s]; __syncthreads(); }
  const float inv = 1.f / red[0];
  __syncthreads();
  if (tid < CS) pr[tid] *= inv;
  if (tid < DD) red[tid] = (tid < CS) ? pr[tid] * yv[tid] : 0.f;
  __syncthreads();
  for (int s = 64; s > 0; s >>= 1) { if (tid < s) red[tid] += red[tid + s]; __syncthreads(); }
  if (tid == 0) smv[0] = red[0];
  __hip_bfloat16* db16 = (__hip_bfloat16*)diffs;
  {
    float4 f0s[6], f1s[6];
#pragma unroll
    for (int i = 0; i < 6; ++i) {
      const int gidx = tid + 256 * i;
      const int row = gidx >> 4, c8 = gidx & 15;
      f0s[i] = *(const float4*)(diffs + row * 132 + c8 * 8);
      f1s[i] = *(const float4*)(diffs + row * 132 + c8 * 8 + 4);
    }
    __syncthreads();
#pragma unroll
    for (int i = 0; i < 6; ++i) {
      const int gidx = tid + 256 * i;
      const int row = gidx >> 4, c8 = gidx & 15;
      *(uint4*)(db16 + row * LDB + c8 * 8) = pack8(f0s[i], f1s[i]);
    }
  }
  __syncthreads();
  {
    const int w = tid >> 6, l = tid & 63;
    const int lr = l & 15, lg = l >> 4;
    const int u0 = w * 64;
    bf16x8 af[6][4];
#pragma unroll
    for (int mt = 0; mt < 6; ++mt)
#pragma unroll
      for (int k = 0; k < 4; ++k)
        af[mt][k] = *(const bf16x8*)(db16 + (mt * 16 + lr) * LDB + k * 32 + lg * 8);
#pragma unroll
    for (int nt = 0; nt < 4; ++nt) {
      const int u = u0 + nt * 16 + lr;
      bf16x8 bfr[4];
#pragma unroll
      for (int k = 0; k < 4; ++k)
        bfr[k] = *(const bf16x8*)(Tw1t + (size_t)u * DD + k * 32 + lg * 8);
      const float bb = Tb1[u];
      float qacc = 0.f;
#pragma unroll
      for (int mt = 0; mt < 6; ++mt) {
        f32x4 acc = {};
#pragma unroll
        for (int k = 0; k < 4; ++k)
          acc = __builtin_amdgcn_mfma_f32_16x16x32_bf16(af[mt][k], bfr[k], acc, 0, 0, 0);
#pragma unroll
        for (int r = 0; r < 4; ++r) {
          const int c = mt * 16 + lg * 4 + r;
          qacc += pr[c] * fmaxf(acc[r] + bb, 0.f);
        }
      }
      qacc += __shfl_xor(qacc, 16);
      qacc += __shfl_xor(qacc, 32);
      if (lg == 0) qs[u] = qacc;
    }
  }
  __syncthreads();
  if (tid < DD) {
    const int d = tid;
    float cx = smv[0] * labw[d] + labb[d];
    for (int u4 = 0; u4 < 64; ++u4) {
      float4 q4 = *(const float4*)(&qs[u4 * 4]);
      cx += q4.x * Tw2[(u4 * 4 + 0) * DD + d];
      cx += q4.y * Tw2[(u4 * 4 + 1) * DD + d];
      cx += q4.z * Tw2[(u4 * 4 + 2) * DD + d];
      cx += q4.w * Tw2[(u4 * 4 + 3) * DD + d];
    }
    xrow[d] = xv[d] + cx;
  }
  __syncthreads();
  if (tid < DD) red[tid] = xrow[tid];
  __syncthreads();
  for (int s = 64; s > 0; s >>= 1) { if (tid < s) red[tid] += red[tid + s]; __syncthreads(); }
  const float m1 = red[0] * (1.f / 128.f);
  __syncthreads();
  if (tid < DD) { float d = xrow[tid] - m1; red[tid] = d * d; }
  __syncthreads();
  for (int s = 64; s > 0; s >>= 1) { if (tid < s) red[tid] += red[tid + s]; __syncthreads(); }
  const float rstd1 = 1.f / sqrtf(red[0] * (1.f / 128.f) + 1e-5f);
  __syncthreads();
  if (tid < DD) hln[tid] = (xrow[tid] - m1) * rstd1 * pg[tid] + pb[tid];
  __syncthreads();
  {
    const int u = tid;
    float s = pb1[u];
    for (int j4 = 0; j4 < 32; ++j4) {
      float4 h4 = *(const float4*)(hln + j4 * 4);
      s += h4.x * pw1[(j4 * 4 + 0) * DBH + u];
      s += h4.y * pw1[(j4 * 4 + 1) * DBH + u];
      s += h4.z * pw1[(j4 * 4 + 2) * DBH + u];
      s += h4.w * pw1[(j4 * 4 + 3) * DBH + u];
    }
    t2[u] = fmaxf(s, 0.f);
  }
  __syncthreads();
  if (tid < DD) {
    const int d = tid;
    float s = pb2[d];
    for (int u4 = 0; u4 < 64; ++u4) {
      float4 t4 = *(const float4*)(t2 + u4 * 4);
      s += t4.x * pw2[(u4 * 4 + 0) * DD + d];
      s += t4.y * pw2[(u4 * 4 + 1) * DD + d];
      s += t4.z * pw2[(u4 * 4 + 2) * DD + d];
      s += t4.w * pw2[(u4 * 4 + 3) * DD + d];
    }
    x2[d] = xrow[d] + s;
  }
  __syncthreads();
  if (tid < DD) red[tid] = x2[tid];
  __syncthreads();
  for (int s = 64; s > 0; s >>= 1) { if (tid < s) red[tid] += red[tid + s]; __syncthreads(); }
  const float m2 = red[0] * (1.f / 128.f);
  __syncthreads();
  if (tid < DD) { float d = x2[tid] - m2; red[tid] = d * d; }
  __syncthreads();
  for (int s = 64; s > 0; s >>= 1) { if (tid < s) red[tid] += red[tid + s]; __syncthreads(); }
  const float rstd2 = 1.f / sqrtf(red[0] * (1.f / 128.f) + 1e-5f);
  __syncthreads();
  if (tid < DD) {
    float z = (x2[tid] - m2) * rstd2 * hg[tid] + hb[tid];
    z = fmaxf(z, 0.f);
    red[tid] = z * hw[tid];
  }
  __syncthreads();
  for (int s = 64; s > 0; s >>= 1) { if (tid < s) red[tid] += red[tid + s]; __syncthreads(); }
  if (tid == 0) OUT[b] = red[0] + hbias[0];
}

// ======================================= launcher =======================================
extern "C" void kernel_launch(void* const* d_in, const int* in_sizes, int n_in,
                              void* d_out, int out_size, void* d_ws, size_t ws_size,
                              hipStream_t stream) {
  (void)in_sizes; (void)n_in; (void)out_size; (void)ws_size;
  const float* x_num      = (const float*)d_in[0];
  const float* cand_x     = (const float*)d_in[1];
  const float* cand_y     = (const float*)d_in[2];
  const float* W_in       = (const float*)d_in[3];
  const float* b_in       = (const float*)d_in[4];
  const float* enc_w1     = (const float*)d_in[5];
  const float* enc_b1     = (const float*)d_in[6];
  const float* enc_w2     = (const float*)d_in[7];
  const float* enc_b2     = (const float*)d_in[8];
  const float* ln_mix_g   = (const float*)d_in[9];
  const float* ln_mix_b   = (const float*)d_in[10];
  const float* K_w        = (const float*)d_in[11];
  const float* K_b        = (const float*)d_in[12];
  const float* lab_w      = (const float*)d_in[13];
  const float* lab_b      = (const float*)d_in[14];
  const float* T_w1       = (const float*)d_in[15];
  const float* T_b1       = (const float*)d_in[16];
  const float* T_w2       = (const float*)d_in[17];
  const float* pred_ln_g  = (const float*)d_in[18];
  const float* pred_ln_b  = (const float*)d_in[19];
  const float* pred_w1    = (const float*)d_in[20];
  const float* pred_b1    = (const float*)d_in[21];
  const float* pred_w2    = (const float*)d_in[22];
  const float* pred_b2    = (const float*)d_in[23];
  const float* head_ln_g  = (const float*)d_in[24];
  const float* head_ln_b  = (const float*)d_in[25];
  const float* head_w     = (const float*)d_in[26];
  const float* head_b     = (const float*)d_in[27];
  float* out = (float*)d_out;

  char* w8 = (char*)d_ws;
  size_t off = 0;
  float* cand_k = (float*)(w8 + off);              off += (size_t)NC * DD * 4;
  float* cand_ck2 = (float*)(w8 + off);            off += (size_t)NCP * 4 + 256;
  float* xh = (float*)(w8 + off);                  off += (size_t)BB * DD * 4;
  float* xk = (float*)(w8 + off);                  off += (size_t)BB * DD * 4;
  float* xk2 = (float*)(w8 + off);                 off += 4096;
  __hip_bfloat16* xkb16 = (__hip_bfloat16*)(w8 + off); off += (size_t)BB * DD * 2;
  int* idx_all = (int*)(w8 + off);                 off += (size_t)BB * CS * 4;
  __hip_bfloat16* w1t = (__hip_bfloat16*)(w8 + off); off += (size_t)DBH * DD * 2;
  __hip_bfloat16* w2t = (__hip_bfloat16*)(w8 + off); off += (size_t)DD * DBH * 2;
  __hip_bfloat16* kwt = (__hip_bfloat16*)(w8 + off); off += (size_t)DD * DD * 2;
  __hip_bfloat16* tw1t = (__hip_bfloat16*)(w8 + off); off += (size_t)DBH * DD * 2;
  char* big = w8 + off;
  // timeline overlay in `big`:
  //   encoder phase : cand_h [NC,128] f32                      (0 .. 102.4 MB)
  //   selection     : candb [1024][CROW] u64 (51.4 MB) at 0; rmaxpart/cnt2/cutF at +56 MB
  //   always        : ckb16 [NCP,128] bf16 at +102.4 MB
  float* cand_h = (float*)big;
  unsigned long long* candb = (unsigned long long*)big;
  float* rmaxpart = (float*)(big + (size_t)56 * 1024 * 1024);            // 803 KB
  int* cnt2 = (int*)(big + (size_t)57 * 1024 * 1024);                    // 803 KB
  float* cutF = (float*)(big + (size_t)58 * 1024 * 1024);                // 4 KB
  __hip_bfloat16* ckb16 = (__hip_bfloat16*)(big + (size_t)NC * DD * 4);

  k_prep<<<128, 256, 0, stream>>>(enc_w1, enc_w2, K_w, T_w1, w1t, w2t, kwt, tw1t);
  k_pad<<<32, 256, 0, stream>>>(ckb16, cand_ck2);
  // ---- encoder: candidates ----
  k_e1<<<NC / 32, 256, 0, stream>>>(cand_x, W_in, b_in, cand_h);
  k_e23m<<<NC / 64, 256, 0, stream>>>(cand_h, w1t, enc_b1, w2t, enc_b2);
  k_e4m<<<NC / 64, 256, 0, stream>>>(cand_h, ln_mix_g, ln_mix_b, kwt, K_b,
                                     cand_k, ckb16, cand_ck2);
  // ---- encoder: queries ----
  k_e1<<<BB / 32, 256, 0, stream>>>(x_num, W_in, b_in, xh);
  k_e23m<<<BB / 64, 256, 0, stream>>>(xh, w1t, enc_b1, w2t, enc_b2);
  k_e4m<<<BB / 64, 256, 0, stream>>>(xh, ln_mix_g, ln_mix_b, kwt, K_b,
                                     xk, xkb16, xk2);
  // ---- scores + top-96: atomic-free two-pass, XCD-affine, async B staging ----
  k_simsA<<<1600, 256, 0, stream>>>(xkb16, ckb16, cand_ck2, rmaxpart);
  k_rmax<<<4, 256, 0, stream>>>(rmaxpart, cutF);
  k_simsB<<<1600, 256, 0, stream>>>(xkb16, ckb16, cand_ck2, cutF, candb, cnt2);
  k_sortB<<<BB, 256, 0, stream>>>(candb, cnt2, idx_all);
  // ---- gather + context + head ----
  k_final<<<BB, 256, 0, stream>>>(xh, xk, cand_k, cand_y, idx_all,
                                  tw1t, T_b1, T_w2, lab_w, lab_b,
                                  pred_ln_g, pred_ln_b, pred_w1, pred_b1, pred_w2, pred_b2,
                                  head_ln_g, head_ln_b, head_w, head_b, out);
}

// Round 19
// 574.747 us; speedup vs baseline: 1.1784x; 1.0130x over previous
//
#include <hip/hip_runtime.h>
#include <hip/hip_bf16.h>

#define NC 200000
#define NCP 200064
#define NCT 1563
#define NRG 196
#define CTR 8
#define SCAP2 32
#define CROW (NRG * SCAP2)   // 6272 slots per row
#define SREG 25              // ceil(6272/256)
#define BB 1024
#define DD 128
#define DBH 256
#define CS 96

typedef __attribute__((ext_vector_type(8))) short bf16x8;
typedef __attribute__((ext_vector_type(4))) float f32x4;

#define LDH 136
#define LDU 264

__device__ inline uint4 pack8(const float4 a, const float4 b) {
  union { __hip_bfloat16 h[8]; uint4 v; } r;
  r.h[0] = __float2bfloat16(a.x); r.h[1] = __float2bfloat16(a.y);
  r.h[2] = __float2bfloat16(a.z); r.h[3] = __float2bfloat16(a.w);
  r.h[4] = __float2bfloat16(b.x); r.h[5] = __float2bfloat16(b.y);
  r.h[6] = __float2bfloat16(b.z); r.h[7] = __float2bfloat16(b.w);
  return r.v;
}

__device__ inline unsigned encf(float v) {
  unsigned b = __float_as_uint(v);
  return (b & 0x80000000u) ? ~b : (b | 0x80000000u);
}
__device__ inline float decf(unsigned u) {
  return __uint_as_float((u & 0x80000000u) ? (u ^ 0x80000000u) : ~u);
}
// key: high32 = ~enc(v)  (u64-ascending == value-descending), low32 = idx
__device__ inline unsigned long long mkkey(float v, int idx) {
  unsigned u = encf(v);
  return (((unsigned long long)(~u)) << 32) | (unsigned)idx;
}

// async 16B global -> LDS (wave-uniform LDS base + lane*16)
__device__ inline void gload16(const void* g, void* l) {
  __builtin_amdgcn_global_load_lds((const __attribute__((address_space(1))) void*)g,
                                   (__attribute__((address_space(3))) void*)l, 16, 0, 0);
}

// stage one 128x128 bf16 col-tile (rows n0..n0+127) into buf, source pre-XOR-swizzled
__device__ inline void stageB(const __hip_bfloat16* __restrict__ Bm, int n0,
                              __hip_bfloat16* buf, int w, int l) {
  const char* gbase = (const char*)(Bm + (size_t)n0 * DD);
#pragma unroll
  for (int j = 0; j < 8; ++j) {
    const int r = w * 32 + j * 4 + (l >> 4);
    const int b = ((l & 15) * 16) ^ ((r & 7) << 4);
    gload16(gbase + (size_t)r * 256 + b, (char*)buf + w * 8192 + j * 1024);
  }
}

// ====================== weight prep: bf16 transposed copies ======================
__global__ __launch_bounds__(256) void k_prep(const float* __restrict__ w1,
                                              const float* __restrict__ w2,
                                              const float* __restrict__ kw,
                                              const float* __restrict__ tw1,
                                              __hip_bfloat16* __restrict__ w1t,
                                              __hip_bfloat16* __restrict__ w2t,
                                              __hip_bfloat16* __restrict__ kwt,
                                              __hip_bfloat16* __restrict__ tw1t) {
  const int i = blockIdx.x * 256 + threadIdx.x;
  if (i < 32768) {
    const int u = i >> 7, j = i & 127;
    w1t[i] = __float2bfloat16(w1[j * DBH + u]);
    tw1t[i] = __float2bfloat16(tw1[j * DBH + u]);
  }
  if (i < 32768) {
    const int d = i >> 8, u = i & 255;
    w2t[i] = __float2bfloat16(w2[u * DD + d]);
  }
  if (i < 16384) {
    const int d = i >> 7, j = i & 127;
    kwt[i] = __float2bfloat16(kw[j * DD + d]);
  }
}

// ================= pad rows [NC, NCP): zero keys, huge ck2 (scores ~ -5e8) =================
__global__ __launch_bounds__(256) void k_pad(__hip_bfloat16* __restrict__ ckb16,
                                             float* __restrict__ ck2) {
  const int i = blockIdx.x * 256 + threadIdx.x;
  if (i < (NCP - NC) * DD) ckb16[(size_t)NC * DD + i] = __float2bfloat16(0.f);
  if (i < (NCP - NC)) ck2[NC + i] = 1e9f;
}

// ============================ encoder stage 1: H = X @ W_in + b ============================
__global__ __launch_bounds__(256) void k_e1(const float* __restrict__ X,
                                            const float* __restrict__ W,
                                            const float* __restrict__ bias,
                                            float* __restrict__ H) {
  __shared__ float Xs[32 * 32];
  const int tid = threadIdx.x;
  const int r0 = blockIdx.x * 32;
  ((float4*)Xs)[tid] = ((const float4*)(X + (size_t)r0 * 32))[tid];
  __syncthreads();
  const int d0 = tid & 63;
  const int rh = tid >> 6;
  float acc0[8], acc1[8];
  const float b0 = bias[d0], b1 = bias[d0 + 64];
#pragma unroll
  for (int r = 0; r < 8; ++r) { acc0[r] = b0; acc1[r] = b1; }
#pragma unroll
  for (int k4 = 0; k4 < 8; ++k4) {
    float w0[4], w1[4];
#pragma unroll
    for (int kk = 0; kk < 4; ++kk) {
      w0[kk] = W[(k4 * 4 + kk) * DD + d0];
      w1[kk] = W[(k4 * 4 + kk) * DD + d0 + 64];
    }
#pragma unroll
    for (int r = 0; r < 8; ++r) {
      float4 x4 = ((const float4*)(Xs + (rh * 8 + r) * 32))[k4];
      acc0[r] += x4.x * w0[0] + x4.y * w0[1] + x4.z * w0[2] + x4.w * w0[3];
      acc1[r] += x4.x * w1[0] + x4.y * w1[1] + x4.z * w1[2] + x4.w * w1[3];
    }
  }
#pragma unroll
  for (int r = 0; r < 8; ++r) {
    const size_t row = (size_t)(r0 + rh * 8 + r);
    H[row * DD + d0] = acc0[r];
    H[row * DD + d0 + 64] = acc1[r];
  }
}

// ============== encoder stage 2+3 (MFMA): H = H + relu(H@W1 + b1)@W2 + b2 ==============
__global__ __launch_bounds__(256) void k_e23m(float* __restrict__ H,
                                              const __hip_bfloat16* __restrict__ W1t,
                                              const float* __restrict__ B1,
                                              const __hip_bfloat16* __restrict__ W2t,
                                              const float* __restrict__ B2) {
  __shared__ __hip_bfloat16 Hs[64 * LDH];
  __shared__ __hip_bfloat16 Us[64 * LDU];
  const int tid = threadIdx.x;
  const int r0 = blockIdx.x * 64;
#pragma unroll
  for (int i = 0; i < 4; ++i) {
    const int e8 = i * 256 + tid;
    const int row = e8 >> 4, c8 = e8 & 15;
    const float* src = H + (size_t)(r0 + row) * DD + c8 * 8;
    float4 f0 = *(const float4*)(src);
    float4 f1 = *(const float4*)(src + 4);
    *(uint4*)(Hs + row * LDH + c8 * 8) = pack8(f0, f1);
  }
  __syncthreads();
  const int l = tid & 63, w = tid >> 6;
  const int lr = l & 15, lg = l >> 4;
  {  // phase 1: U = relu(H @ W1 + b1)
    f32x4 acc[4][4] = {};
#pragma unroll
    for (int kk = 0; kk < 4; ++kk) {
      bf16x8 a[4], b[4];
#pragma unroll
      for (int mi = 0; mi < 4; ++mi)
        a[mi] = *(const bf16x8*)(Hs + (mi * 16 + lr) * LDH + kk * 32 + lg * 8);
#pragma unroll
      for (int ni = 0; ni < 4; ++ni)
        b[ni] = *(const bf16x8*)(W1t + (size_t)(w * 64 + ni * 16 + lr) * DD + kk * 32 + lg * 8);
#pragma unroll
      for (int mi = 0; mi < 4; ++mi)
#pragma unroll
        for (int ni = 0; ni < 4; ++ni)
          acc[mi][ni] = __builtin_amdgcn_mfma_f32_16x16x32_bf16(a[mi], b[ni], acc[mi][ni], 0, 0, 0);
    }
#pragma unroll
    for (int ni = 0; ni < 4; ++ni) {
      const int col = w * 64 + ni * 16 + lr;
      const float bb = B1[col];
#pragma unroll
      for (int mi = 0; mi < 4; ++mi)
#pragma unroll
        for (int r = 0; r < 4; ++r) {
          const int row = mi * 16 + lg * 4 + r;
          Us[row * LDU + col] = __float2bfloat16(fmaxf(acc[mi][ni][r] + bb, 0.f));
        }
    }
  }
  __syncthreads();
  {  // phase 2: H += U @ W2 + b2
    f32x4 acc[4][2] = {};
#pragma unroll
    for (int kk = 0; kk < 8; ++kk) {
      bf16x8 a[4], b[2];
#pragma unroll
      for (int mi = 0; mi < 4; ++mi)
        a[mi] = *(const bf16x8*)(Us + (mi * 16 + lr) * LDU + kk * 32 + lg * 8);
#pragma unroll
      for (int ni = 0; ni < 2; ++ni)
        b[ni] = *(const bf16x8*)(W2t + (size_t)(w * 32 + ni * 16 + lr) * DBH + kk * 32 + lg * 8);
#pragma unroll
      for (int mi = 0; mi < 4; ++mi)
#pragma unroll
        for (int ni = 0; ni < 2; ++ni)
          acc[mi][ni] = __builtin_amdgcn_mfma_f32_16x16x32_bf16(a[mi], b[ni], acc[mi][ni], 0, 0, 0);
    }
#pragma unroll
    for (int ni = 0; ni < 2; ++ni) {
      const int col = w * 32 + ni * 16 + lr;
      const float bb = B2[col];
#pragma unroll
      for (int mi = 0; mi < 4; ++mi)
#pragma unroll
        for (int r = 0; r < 4; ++r) {
          const int row = mi * 16 + lg * 4 + r;
          const size_t g = (size_t)(r0 + row) * DD + col;
          H[g] = H[g] + acc[mi][ni][r] + bb;
        }
    }
  }
}

// ====== encoder stage 4 (MFMA): K = LN(H)@Kw + Kb ; bf16 copy + rowwise sum(K^2) ======
__global__ __launch_bounds__(256) void k_e4m(const float* __restrict__ H,
                                             const float* __restrict__ g,
                                             const float* __restrict__ bln,
                                             const __hip_bfloat16* __restrict__ Kwt,
                                             const float* __restrict__ Kb,
                                             float* __restrict__ Kout,
                                             __hip_bfloat16* __restrict__ Kb16,
                                             float* __restrict__ k2out) {
  __shared__ __hip_bfloat16 Ls[64 * LDH];
  __shared__ float k2s[64];
  const int tid = threadIdx.x;
  const int r0 = blockIdx.x * 64;
  if (tid < 64) k2s[tid] = 0.f;
  {
    const int row = tid >> 2, q = tid & 3;
    const float* hr = H + (size_t)(r0 + row) * DD + q * 32;
    float v[32];
#pragma unroll
    for (int i = 0; i < 8; ++i) {
      float4 f = ((const float4*)hr)[i];
      v[i * 4 + 0] = f.x; v[i * 4 + 1] = f.y; v[i * 4 + 2] = f.z; v[i * 4 + 3] = f.w;
    }
    float s = 0.f;
#pragma unroll
    for (int i = 0; i < 32; ++i) s += v[i];
    s += __shfl_xor(s, 1); s += __shfl_xor(s, 2);
    const float mean = s * (1.f / 128.f);
    float vs = 0.f;
#pragma unroll
    for (int i = 0; i < 32; ++i) { float d = v[i] - mean; vs += d * d; }
    vs += __shfl_xor(vs, 1); vs += __shfl_xor(vs, 2);
    const float rstd = 1.f / sqrtf(vs * (1.f / 128.f) + 1e-5f);
#pragma unroll
    for (int i = 0; i < 4; ++i) {
      float t[8];
#pragma unroll
      for (int j = 0; j < 8; ++j) {
        const int col = q * 32 + i * 8 + j;
        t[j] = (v[i * 8 + j] - mean) * rstd * g[col] + bln[col];
      }
      float4 f0 = {t[0], t[1], t[2], t[3]}, f1 = {t[4], t[5], t[6], t[7]};
      *(uint4*)(Ls + row * LDH + q * 32 + i * 8) = pack8(f0, f1);
    }
  }
  __syncthreads();
  const int l = tid & 63, w = tid >> 6;
  const int lr = l & 15, lg = l >> 4;
  f32x4 acc[4][2] = {};
#pragma unroll
  for (int kk = 0; kk < 4; ++kk) {
    bf16x8 a[4], b[2];
#pragma unroll
    for (int mi = 0; mi < 4; ++mi)
      a[mi] = *(const bf16x8*)(Ls + (mi * 16 + lr) * LDH + kk * 32 + lg * 8);
#pragma unroll
    for (int ni = 0; ni < 2; ++ni)
      b[ni] = *(const bf16x8*)(Kwt + (size_t)(w * 32 + ni * 16 + lr) * DD + kk * 32 + lg * 8);
#pragma unroll
    for (int mi = 0; mi < 4; ++mi)
#pragma unroll
      for (int ni = 0; ni < 2; ++ni)
        acc[mi][ni] = __builtin_amdgcn_mfma_f32_16x16x32_bf16(a[mi], b[ni], acc[mi][ni], 0, 0, 0);
  }
  float p[4][4];
#pragma unroll
  for (int mi = 0; mi < 4; ++mi)
#pragma unroll
    for (int r = 0; r < 4; ++r) p[mi][r] = 0.f;
#pragma unroll
  for (int ni = 0; ni < 2; ++ni) {
    const int col = w * 32 + ni * 16 + lr;
    const float kb = Kb[col];
#pragma unroll
    for (int mi = 0; mi < 4; ++mi)
#pragma unroll
      for (int r = 0; r < 4; ++r) {
        const float val = acc[mi][ni][r] + kb;
        const int row = mi * 16 + lg * 4 + r;
        const size_t gg = (size_t)(r0 + row) * DD + col;
        Kout[gg] = val;
        Kb16[gg] = __float2bfloat16(val);
        p[mi][r] += val * val;
      }
  }
#pragma unroll
  for (int mi = 0; mi < 4; ++mi)
#pragma unroll
    for (int r = 0; r < 4; ++r) {
      float t = p[mi][r];
      t += __shfl_xor(t, 1); t += __shfl_xor(t, 2);
      t += __shfl_xor(t, 4); t += __shfl_xor(t, 8);
      if (lr == 0) atomicAdd(&k2s[mi * 16 + lg * 4 + r], t);
    }
  __syncthreads();
  if (tid < 64) k2out[r0 + tid] = k2s[tid];
}

// ==== pass 1: (rowtile, range) blocks, XCD-affine; DOUBLE-BUFFERED async B staging ====
// T3 minimum 2-phase: issue tile t+1's global_load_lds BEFORE computing tile t;
// single __syncthreads per iteration drains them after compute (loads in flight
// during MFMA+emit instead of idling).
__global__ __launch_bounds__(256) void k_simsA(const __hip_bfloat16* __restrict__ A,
                                               const __hip_bfloat16* __restrict__ Bm,
                                               const float* __restrict__ ck2,
                                               float* __restrict__ rmaxpart) {
  __shared__ __hip_bfloat16 Bs[2][128 * 128];  // 64 KB, content XOR-swizzled per row
  __shared__ float part[2][128];
  const int tid = threadIdx.x;
  const int bid = blockIdx.x;         // grid 1600 = 25 x 8rt x 8x
  const int gq = bid >> 6, rt = (bid >> 3) & 7, xq = bid & 7;
  const int range = gq * 8 + xq;
  if (range >= NRG) return;
  const int m0 = rt * 128;
  const int l = tid & 63, w = tid >> 6;
  const int wm = w >> 1, wn = w & 1;
  const int lr = l & 15, lg = l >> 4;
  const int ct0 = range * CTR;
  const int nt = (ct0 + CTR <= NCT) ? CTR : (NCT - ct0);
  bf16x8 a[4][4];
#pragma unroll
  for (int mi = 0; mi < 4; ++mi) {
    const __hip_bfloat16* ar = A + (size_t)(m0 + wm * 64 + mi * 16 + lr) * DD + lg * 8;
#pragma unroll
    for (int kk = 0; kk < 4; ++kk) a[mi][kk] = *(const bf16x8*)(ar + kk * 32);
  }
  float vmax[4][4];
#pragma unroll
  for (int mi = 0; mi < 4; ++mi)
#pragma unroll
    for (int r = 0; r < 4; ++r) vmax[mi][r] = -1e30f;
  stageB(Bm, ct0 * 128, Bs[0], w, l);
  __syncthreads();                       // drain tile 0
  int cur = 0;
  for (int i = 0; i < nt; ++i) {
    const int n0 = (ct0 + i) * 128;
    float c2l[4];                        // issued FIRST: their wait is vmcnt(8), not a drain
#pragma unroll
    for (int ni = 0; ni < 4; ++ni) c2l[ni] = 0.5f * ck2[n0 + wn * 64 + ni * 16 + lr];
    if (i + 1 < nt) stageB(Bm, n0 + 128, Bs[cur ^ 1], w, l);  // async, overlaps compute
    f32x4 acc[4][4] = {};
#pragma unroll
    for (int kk = 0; kk < 4; ++kk) {
      bf16x8 b[4];
#pragma unroll
      for (int ni = 0; ni < 4; ++ni) {
        const int row = wn * 64 + ni * 16 + lr;
        const int boff = (kk * 64 + lg * 16) ^ ((row & 7) << 4);
        b[ni] = *(const bf16x8*)((const char*)Bs[cur] + row * 256 + boff);
      }
#pragma unroll
      for (int mi = 0; mi < 4; ++mi)
#pragma unroll
        for (int ni = 0; ni < 4; ++ni)
          acc[mi][ni] = __builtin_amdgcn_mfma_f32_16x16x32_bf16(a[mi][kk], b[ni], acc[mi][ni], 0, 0, 0);
    }
#pragma unroll
    for (int mi = 0; mi < 4; ++mi)
#pragma unroll
      for (int r = 0; r < 4; ++r)
#pragma unroll
        for (int ni = 0; ni < 4; ++ni)
          vmax[mi][r] = fmaxf(vmax[mi][r], acc[mi][ni][r] - c2l[ni]);
    __syncthreads();                     // drains tile i+1; protects buffers
    cur ^= 1;
  }
#pragma unroll
  for (int mi = 0; mi < 4; ++mi)
#pragma unroll
    for (int r = 0; r < 4; ++r) {
      float v = vmax[mi][r];
#pragma unroll
      for (int mk = 1; mk < 16; mk <<= 1) v = fmaxf(v, __shfl_xor(v, mk));
      if (lr == 0) part[wn][wm * 64 + mi * 16 + lg * 4 + r] = v;
    }
  __syncthreads();
  if (tid < 128)
    rmaxpart[(size_t)range * BB + m0 + tid] = fmaxf(part[0][tid], part[1][tid]);
}

// ==== reduce partial maxes -> per-row conservative f32 cutoff ====
__global__ __launch_bounds__(256) void k_rmax(const float* __restrict__ rmaxpart,
                                              float* __restrict__ cutF) {
  const int row = blockIdx.x * 256 + threadIdx.x;
  float m = -1e30f;
  for (int j = 0; j < NRG; ++j) m = fmaxf(m, rmaxpart[(size_t)j * BB + row]);
  const float t = m - 7.0f;
  cutF[row] = t - (fabsf(t) + 8.0f) * 0.00390625f - 1e-5f;  // safe f32 lower bound
}

// ==== pass 2: same mapping; DOUBLE-BUFFERED staging; block-private segments ====
__global__ __launch_bounds__(256) void k_simsB(const __hip_bfloat16* __restrict__ A,
                                               const __hip_bfloat16* __restrict__ Bm,
                                               const float* __restrict__ ck2,
                                               const float* __restrict__ cutF,
                                               unsigned long long* __restrict__ cand,
                                               int* __restrict__ cnt2) {
  __shared__ __hip_bfloat16 Bs[2][128 * 128];  // 64 KB, content XOR-swizzled per row
  __shared__ float cut_s[128];
  __shared__ int lcnt[128];
  const int tid = threadIdx.x;
  const int bid = blockIdx.x;
  const int gq = bid >> 6, rt = (bid >> 3) & 7, xq = bid & 7;
  const int range = gq * 8 + xq;
  if (range >= NRG) return;
  const int m0 = rt * 128;
  if (tid < 128) { cut_s[tid] = cutF[m0 + tid]; lcnt[tid] = 0; }
  const int l = tid & 63, w = tid >> 6;
  const int wm = w >> 1, wn = w & 1;
  const int lr = l & 15, lg = l >> 4;
  const int ct0 = range * CTR;
  const int nt = (ct0 + CTR <= NCT) ? CTR : (NCT - ct0);
  bf16x8 a[4][4];
#pragma unroll
  for (int mi = 0; mi < 4; ++mi) {
    const __hip_bfloat16* ar = A + (size_t)(m0 + wm * 64 + mi * 16 + lr) * DD + lg * 8;
#pragma unroll
    for (int kk = 0; kk < 4; ++kk) a[mi][kk] = *(const bf16x8*)(ar + kk * 32);
  }
  stageB(Bm, ct0 * 128, Bs[0], w, l);
  __syncthreads();                       // drain tile 0 (+ cut_s/lcnt visible)
  int cur = 0;
  for (int i = 0; i < nt; ++i) {
    const int n0 = (ct0 + i) * 128;
    float c2l[4];                        // issued FIRST (see pass 1)
#pragma unroll
    for (int ni = 0; ni < 4; ++ni) c2l[ni] = 0.5f * ck2[n0 + wn * 64 + ni * 16 + lr];
    if (i + 1 < nt) stageB(Bm, n0 + 128, Bs[cur ^ 1], w, l);  // async, overlaps compute
    f32x4 acc[4][4] = {};
#pragma unroll
    for (int kk = 0; kk < 4; ++kk) {
      bf16x8 b[4];
#pragma unroll
      for (int ni = 0; ni < 4; ++ni) {
        const int row = wn * 64 + ni * 16 + lr;
        const int boff = (kk * 64 + lg * 16) ^ ((row & 7) << 4);
        b[ni] = *(const bf16x8*)((const char*)Bs[cur] + row * 256 + boff);
      }
#pragma unroll
      for (int mi = 0; mi < 4; ++mi)
#pragma unroll
        for (int ni = 0; ni < 4; ++ni)
          acc[mi][ni] = __builtin_amdgcn_mfma_f32_16x16x32_bf16(a[mi][kk], b[ni], acc[mi][ni], 0, 0, 0);
    }
#pragma unroll
    for (int ni = 0; ni < 4; ++ni) {
      const int gcol = n0 + wn * 64 + ni * 16 + lr;
#pragma unroll
      for (int mi = 0; mi < 4; ++mi)
#pragma unroll
        for (int r = 0; r < 4; ++r) {
          const int lrow = wm * 64 + mi * 16 + lg * 4 + r;
          const float x = acc[mi][ni][r] - c2l[ni];
          if (x >= cut_s[lrow]) {
            const float v = __bfloat162float(__float2bfloat16(x));
            const int q = atomicAdd(&lcnt[lrow], 1);    // block-local LDS atomic
            if (q < SCAP2)
              cand[(size_t)(m0 + lrow) * CROW + range * SCAP2 + q] = mkkey(v, gcol);
          }
        }
    }
    __syncthreads();                     // drains tile i+1; protects buffers
    cur ^= 1;
  }
  if (tid < 128) {
    const int n = lcnt[tid];
    cnt2[(size_t)range * BB + m0 + tid] = n < SCAP2 ? n : SCAP2;
  }
}

// ===== select: compact 196 segments, then exact top-96 via bitwise binary-search =====
__global__ __launch_bounds__(256) void k_sortB(const unsigned long long* __restrict__ cand,
                                               const int* __restrict__ cnt2,
                                               int* __restrict__ idx_out) {
  __shared__ unsigned long long keys[CROW];  // 50.2 KB
  __shared__ int csum[NRG + 1];
  __shared__ int wred[40][4];
  __shared__ int outl[128];
  __shared__ int outc_sh;
  const int tid = threadIdx.x;
  const int wid = tid >> 6, lane = tid & 63;
  const int row = blockIdx.x;
  if (tid < NRG) csum[tid] = cnt2[(size_t)tid * BB + row];
  __syncthreads();
  if (tid == 0) {
    int s = 0;
    for (int j = 0; j < NRG; ++j) { const int c = csum[j]; csum[j] = s; s += c; }
    csum[NRG] = s;
  }
  __syncthreads();
  const int n = csum[NRG];
  if (tid < NRG) {
    const int base = csum[tid], c = csum[tid + 1] - base;
    const unsigned long long* src = cand + (size_t)row * CROW + tid * SCAP2;
    for (int j = 0; j < c; ++j) keys[base + j] = src[j];
  }
  __syncthreads();

  unsigned v16l[SREG];
  int idl[SREG];
#pragma unroll
  for (int s = 0; s < SREG; ++s) {
    const int i = tid + s * 256;
    if (i < n) {
      const unsigned long long k = keys[i];
      v16l[s] = (~(unsigned)(k >> 32)) >> 16;
      idl[s] = (int)(k & 0xFFFFFFFFu);
    } else {
      v16l[s] = 0u;
      idl[s] = 0x7FFFFFFF;
    }
  }

  int pass = 0;
  unsigned prefix = 0;
  int need = CS;
#pragma unroll
  for (int b = 15; b >= 0; --b) {
    int c1 = 0;
#pragma unroll
    for (int s = 0; s < SREG; ++s)
      c1 += ((v16l[s] >> (b + 1)) == prefix && ((v16l[s] >> b) & 1u)) ? 1 : 0;
#pragma unroll
    for (int d = 1; d < 64; d <<= 1) c1 += __shfl_xor(c1, d);
    if (lane == 0) wred[pass][wid] = c1;
    __syncthreads();
    const int cnt1 = wred[pass][0] + wred[pass][1] + wred[pass][2] + wred[pass][3];
    ++pass;
    if (need <= cnt1) prefix = (prefix << 1) | 1u;
    else { need -= cnt1; prefix = (prefix << 1); }
  }
  const unsigned V16star = prefix;

  unsigned iprefix = 0;
  int ineed = need;
#pragma unroll
  for (int b = 17; b >= 0; --b) {
    int c0 = 0;
#pragma unroll
    for (int s = 0; s < SREG; ++s)
      c0 += (v16l[s] == V16star && ((unsigned)idl[s] >> (b + 1)) == iprefix &&
             !(((unsigned)idl[s] >> b) & 1u)) ? 1 : 0;
#pragma unroll
    for (int d = 1; d < 64; d <<= 1) c0 += __shfl_xor(c0, d);
    if (lane == 0) wred[pass][wid] = c0;
    __syncthreads();
    const int cnt0 = wred[pass][0] + wred[pass][1] + wred[pass][2] + wred[pass][3];
    ++pass;
    if (ineed <= cnt0) iprefix = (iprefix << 1);
    else { ineed -= cnt0; iprefix = (iprefix << 1) | 1u; }
  }
  const unsigned ITstar = iprefix;

  if (tid == 0) outc_sh = 0;
  __syncthreads();
#pragma unroll
  for (int s = 0; s < SREG; ++s) {
    if (v16l[s] > V16star || (v16l[s] == V16star && (unsigned)idl[s] <= ITstar)) {
      const int q = atomicAdd(&outc_sh, 1);
      if (q < 128) outl[q] = idl[s];
    }
  }
  __syncthreads();
  const int ne = outc_sh;
  for (int i = tid; i < 128; i += 256)
    if (i >= ne) outl[i] = 0x7FFFFFFF;
  __syncthreads();
  for (int k = 2; k <= 128; k <<= 1) {
    for (int j = k >> 1; j > 0; j >>= 1) {
      if (tid < 128) {
        const int i = tid, ixj = i ^ j;
        if (ixj > i) {
          int a = outl[i], b = outl[ixj];
          const bool up = ((i & k) == 0);
          if ((a > b) == up) { outl[i] = b; outl[ixj] = a; }
        }
      }
      __syncthreads();
    }
  }
  if (tid < CS) {
    int id = outl[tid];
    if ((unsigned)id >= NC) id = 0;
    idx_out[row * CS + tid] = id;
  }
}

// ======== gather + context (MFMA T-MLP) + prediction head ========
#define LDB 136
__global__ __launch_bounds__(256) void k_final(const float* __restrict__ XH,
                                               const float* __restrict__ XK,
                                               const float* __restrict__ CK,
                                               const float* __restrict__ CY,
                                               const int* __restrict__ IDX,
                                               const __hip_bfloat16* __restrict__ Tw1t,
                                               const float* __restrict__ Tb1,
                                               const float* __restrict__ Tw2,
                                               const float* __restrict__ labw,
                                               const float* __restrict__ labb,
                                               const float* __restrict__ pg,
                                               const float* __restrict__ pb,
                                               const float* __restrict__ pw1,
                                               const float* __restrict__ pb1,
                                               const float* __restrict__ pw2,
                                               const float* __restrict__ pb2,
                                               const float* __restrict__ hg,
                                               const float* __restrict__ hb,
                                               const float* __restrict__ hw,
                                               const float* __restrict__ hbias,
                                               float* __restrict__ OUT) {
  __shared__ float diffs[CS * 132];
  __shared__ int ids[CS];
  __shared__ float yv[CS], simc[CS], pr[CS];
  __shared__ float kv[DD], xv[DD];
  __shared__ float qs[DBH];
  __shared__ float xrow[DD], hln[DD], t2[DBH], x2[DD];
  __shared__ float red[DD];
  __shared__ float smv[1];
  const int tid = threadIdx.x;
  const int b = blockIdx.x;
  if (tid < CS) ids[tid] = IDX[b * CS + tid];
  if (tid < DD) { kv[tid] = XK[(size_t)b * DD + tid]; xv[tid] = XH[(size_t)b * DD + tid]; }
  __syncthreads();
  if (tid < CS) yv[tid] = CY[ids[tid]];
  for (int e = tid; e < CS * DD; e += 256) {
    const int c = e >> 7, j = e & 127;
    diffs[c * 132 + j] = kv[j] - CK[(size_t)ids[c] * DD + j];
  }
  __syncthreads();
  if (tid < CS) {
    float s = 0.f;
    for (int j = 0; j < DD; ++j) { float d = diffs[tid * 132 + j]; s -= d * d; }
    simc[tid] = s;
  }
  __syncthreads();
  if (tid < DD) red[tid] = (tid < CS) ? simc[tid] : -1e30f;
  __syncthreads();
  for (int s = 64; s > 0; s >>= 1) { if (tid < s) red[tid] = fmaxf(red[tid], red[tid + s]); __syncthreads(); }
  const float mx = red[0];
  __syncthreads();
  if (tid < DD) red[tid] = (tid < CS) ? expf(simc[tid] - mx) : 0.f;
  if (tid < CS) pr[tid] = expf(simc[tid] - mx);
  __syncthreads();
  for (int s = 64; s > 0; s >>= 1) { if (tid < s) red[tid] += red[tid + s]; __syncthreads(); }
  const float inv = 1.f / red[0];
  __syncthreads();
  if (tid < CS) pr[tid] *= inv;
  if (tid < DD) red[tid] = (tid < CS) ? pr[tid] * yv[tid] : 0.f;
  __syncthreads();
  for (int s = 64; s > 0; s >>= 1) { if (tid < s) red[tid] += red[tid + s]; __syncthreads(); }
  if (tid == 0) smv[0] = red[0];
  __hip_bfloat16* db16 = (__hip_bfloat16*)diffs;
  {
    float4 f0s[6], f1s[6];
#pragma unroll
    for (int i = 0; i < 6; ++i) {
      const int gidx = tid + 256 * i;
      const int row = gidx >> 4, c8 = gidx & 15;
      f0s[i] = *(const float4*)(diffs + row * 132 + c8 * 8);
      f1s[i] = *(const float4*)(diffs + row * 132 + c8 * 8 + 4);
    }
    __syncthreads();
#pragma unroll
    for (int i = 0; i < 6; ++i) {
      const int gidx = tid + 256 * i;
      const int row = gidx >> 4, c8 = gidx & 15;
      *(uint4*)(db16 + row * LDB + c8 * 8) = pack8(f0s[i], f1s[i]);
    }
  }
  __syncthreads();
  {
    const int w = tid >> 6, l = tid & 63;
    const int lr = l & 15, lg = l >> 4;
    const int u0 = w * 64;
    bf16x8 af[6][4];
#pragma unroll
    for (int mt = 0; mt < 6; ++mt)
#pragma unroll
      for (int k = 0; k < 4; ++k)
        af[mt][k] = *(const bf16x8*)(db16 + (mt * 16 + lr) * LDB + k * 32 + lg * 8);
#pragma unroll
    for (int nt = 0; nt < 4; ++nt) {
      const int u = u0 + nt * 16 + lr;
      bf16x8 bfr[4];
#pragma unroll
      for (int k = 0; k < 4; ++k)
        bfr[k] = *(const bf16x8*)(Tw1t + (size_t)u * DD + k * 32 + lg * 8);
      const float bb = Tb1[u];
      float qacc = 0.f;
#pragma unroll
      for (int mt = 0; mt < 6; ++mt) {
        f32x4 acc = {};
#pragma unroll
        for (int k = 0; k < 4; ++k)
          acc = __builtin_amdgcn_mfma_f32_16x16x32_bf16(af[mt][k], bfr[k], acc, 0, 0, 0);
#pragma unroll
        for (int r = 0; r < 4; ++r) {
          const int c = mt * 16 + lg * 4 + r;
          qacc += pr[c] * fmaxf(acc[r] + bb, 0.f);
        }
      }
      qacc += __shfl_xor(qacc, 16);
      qacc += __shfl_xor(qacc, 32);
      if (lg == 0) qs[u] = qacc;
    }
  }
  __syncthreads();
  if (tid < DD) {
    const int d = tid;
    float cx = smv[0] * labw[d] + labb[d];
    for (int u4 = 0; u4 < 64; ++u4) {
      float4 q4 = *(const float4*)(&qs[u4 * 4]);
      cx += q4.x * Tw2[(u4 * 4 + 0) * DD + d];
      cx += q4.y * Tw2[(u4 * 4 + 1) * DD + d];
      cx += q4.z * Tw2[(u4 * 4 + 2) * DD + d];
      cx += q4.w * Tw2[(u4 * 4 + 3) * DD + d];
    }
    xrow[d] = xv[d] + cx;
  }
  __syncthreads();
  if (tid < DD) red[tid] = xrow[tid];
  __syncthreads();
  for (int s = 64; s > 0; s >>= 1) { if (tid < s) red[tid] += red[tid + s]; __syncthreads(); }
  const float m1 = red[0] * (1.f / 128.f);
  __syncthreads();
  if (tid < DD) { float d = xrow[tid] - m1; red[tid] = d * d; }
  __syncthreads();
  for (int s = 64; s > 0; s >>= 1) { if (tid < s) red[tid] += red[tid + s]; __syncthreads(); }
  const float rstd1 = 1.f / sqrtf(red[0] * (1.f / 128.f) + 1e-5f);
  __syncthreads();
  if (tid < DD) hln[tid] = (xrow[tid] - m1) * rstd1 * pg[tid] + pb[tid];
  __syncthreads();
  {
    const int u = tid;
    float s = pb1[u];
    for (int j4 = 0; j4 < 32; ++j4) {
      float4 h4 = *(const float4*)(hln + j4 * 4);
      s += h4.x * pw1[(j4 * 4 + 0) * DBH + u];
      s += h4.y * pw1[(j4 * 4 + 1) * DBH + u];
      s += h4.z * pw1[(j4 * 4 + 2) * DBH + u];
      s += h4.w * pw1[(j4 * 4 + 3) * DBH + u];
    }
    t2[u] = fmaxf(s, 0.f);
  }
  __syncthreads();
  if (tid < DD) {
    const int d = tid;
    float s = pb2[d];
    for (int u4 = 0; u4 < 64; ++u4) {
      float4 t4 = *(const float4*)(t2 + u4 * 4);
      s += t4.x * pw2[(u4 * 4 + 0) * DD + d];
      s += t4.y * pw2[(u4 * 4 + 1) * DD + d];
      s += t4.z * pw2[(u4 * 4 + 2) * DD + d];
      s += t4.w * pw2[(u4 * 4 + 3) * DD + d];
    }
    x2[d] = xrow[d] + s;
  }
  __syncthreads();
  if (tid < DD) red[tid] = x2[tid];
  __syncthreads();
  for (int s = 64; s > 0; s >>= 1) { if (tid < s) red[tid] += red[tid + s]; __syncthreads(); }
  const float m2 = red[0] * (1.f / 128.f);
  __syncthreads();
  if (tid < DD) { float d = x2[tid] - m2; red[tid] = d * d; }
  __syncthreads();
  for (int s = 64; s > 0; s >>= 1) { if (tid < s) red[tid] += red[tid + s]; __syncthreads(); }
  const float rstd2 = 1.f / sqrtf(red[0] * (1.f / 128.f) + 1e-5f);
  __syncthreads();
  if (tid < DD) {
    float z = (x2[tid] - m2) * rstd2 * hg[tid] + hb[tid];
    z = fmaxf(z, 0.f);
    red[tid] = z * hw[tid];
  }
  __syncthreads();
  for (int s = 64; s > 0; s >>= 1) { if (tid < s) red[tid] += red[tid + s]; __syncthreads(); }
  if (tid == 0) OUT[b] = red[0] + hbias[0];
}

// ======================================= launcher =======================================
extern "C" void kernel_launch(void* const* d_in, const int* in_sizes, int n_in,
                              void* d_out, int out_size, void* d_ws, size_t ws_size,
                              hipStream_t stream) {
  (void)in_sizes; (void)n_in; (void)out_size; (void)ws_size;
  const float* x_num      = (const float*)d_in[0];
  const float* cand_x     = (const float*)d_in[1];
  const float* cand_y     = (const float*)d_in[2];
  const float* W_in       = (const float*)d_in[3];
  const float* b_in       = (const float*)d_in[4];
  const float* enc_w1     = (const float*)d_in[5];
  const float* enc_b1     = (const float*)d_in[6];
  const float* enc_w2     = (const float*)d_in[7];
  const float* enc_b2     = (const float*)d_in[8];
  const float* ln_mix_g   = (const float*)d_in[9];
  const float* ln_mix_b   = (const float*)d_in[10];
  const float* K_w        = (const float*)d_in[11];
  const float* K_b        = (const float*)d_in[12];
  const float* lab_w      = (const float*)d_in[13];
  const float* lab_b      = (const float*)d_in[14];
  const float* T_w1       = (const float*)d_in[15];
  const float* T_b1       = (const float*)d_in[16];
  const float* T_w2       = (const float*)d_in[17];
  const float* pred_ln_g  = (const float*)d_in[18];
  const float* pred_ln_b  = (const float*)d_in[19];
  const float* pred_w1    = (const float*)d_in[20];
  const float* pred_b1    = (const float*)d_in[21];
  const float* pred_w2    = (const float*)d_in[22];
  const float* pred_b2    = (const float*)d_in[23];
  const float* head_ln_g  = (const float*)d_in[24];
  const float* head_ln_b  = (const float*)d_in[25];
  const float* head_w     = (const float*)d_in[26];
  const float* head_b     = (const float*)d_in[27];
  float* out = (float*)d_out;

  char* w8 = (char*)d_ws;
  size_t off = 0;
  float* cand_k = (float*)(w8 + off);              off += (size_t)NC * DD * 4;
  float* cand_ck2 = (float*)(w8 + off);            off += (size_t)NCP * 4 + 256;
  float* xh = (float*)(w8 + off);                  off += (size_t)BB * DD * 4;
  float* xk = (float*)(w8 + off);                  off += (size_t)BB * DD * 4;
  float* xk2 = (float*)(w8 + off);                 off += 4096;
  __hip_bfloat16* xkb16 = (__hip_bfloat16*)(w8 + off); off += (size_t)BB * DD * 2;
  int* idx_all = (int*)(w8 + off);                 off += (size_t)BB * CS * 4;
  __hip_bfloat16* w1t = (__hip_bfloat16*)(w8 + off); off += (size_t)DBH * DD * 2;
  __hip_bfloat16* w2t = (__hip_bfloat16*)(w8 + off); off += (size_t)DD * DBH * 2;
  __hip_bfloat16* kwt = (__hip_bfloat16*)(w8 + off); off += (size_t)DD * DD * 2;
  __hip_bfloat16* tw1t = (__hip_bfloat16*)(w8 + off); off += (size_t)DBH * DD * 2;
  char* big = w8 + off;
  // timeline overlay in `big`:
  //   encoder phase : cand_h [NC,128] f32                      (0 .. 102.4 MB)
  //   selection     : candb [1024][CROW] u64 (51.4 MB) at 0; rmaxpart/cnt2/cutF at +56 MB
  //   always        : ckb16 [NCP,128] bf16 at +102.4 MB
  float* cand_h = (float*)big;
  unsigned long long* candb = (unsigned long long*)big;
  float* rmaxpart = (float*)(big + (size_t)56 * 1024 * 1024);            // 803 KB
  int* cnt2 = (int*)(big + (size_t)57 * 1024 * 1024);                    // 803 KB
  float* cutF = (float*)(big + (size_t)58 * 1024 * 1024);                // 4 KB
  __hip_bfloat16* ckb16 = (__hip_bfloat16*)(big + (size_t)NC * DD * 4);

  k_prep<<<128, 256, 0, stream>>>(enc_w1, enc_w2, K_w, T_w1, w1t, w2t, kwt, tw1t);
  k_pad<<<32, 256, 0, stream>>>(ckb16, cand_ck2);
  // ---- encoder: candidates ----
  k_e1<<<NC / 32, 256, 0, stream>>>(cand_x, W_in, b_in, cand_h);
  k_e23m<<<NC / 64, 256, 0, stream>>>(cand_h, w1t, enc_b1, w2t, enc_b2);
  k_e4m<<<NC / 64, 256, 0, stream>>>(cand_h, ln_mix_g, ln_mix_b, kwt, K_b,
                                     cand_k, ckb16, cand_ck2);
  // ---- encoder: queries ----
  k_e1<<<BB / 32, 256, 0, stream>>>(x_num, W_in, b_in, xh);
  k_e23m<<<BB / 64, 256, 0, stream>>>(xh, w1t, enc_b1, w2t, enc_b2);
  k_e4m<<<BB / 64, 256, 0, stream>>>(xh, ln_mix_g, ln_mix_b, kwt, K_b,
                                     xk, xkb16, xk2);
  // ---- scores + top-96: atomic-free two-pass, XCD-affine, double-buffered staging ----
  k_simsA<<<1600, 256, 0, stream>>>(xkb16, ckb16, cand_ck2, rmaxpart);
  k_rmax<<<4, 256, 0, stream>>>(rmaxpart, cutF);
  k_simsB<<<1600, 256, 0, stream>>>(xkb16, ckb16, cand_ck2, cutF, candb, cnt2);
  k_sortB<<<BB, 256, 0, stream>>>(candb, cnt2, idx_all);
  // ---- gather + context + head ----
  k_final<<<BB, 256, 0, stream>>>(xh, xk, cand_k, cand_y, idx_all,
                                  tw1t, T_b1, T_w2, lab_w, lab_b,
                                  pred_ln_g, pred_ln_b, pred_w1, pred_b1, pred_w2, pred_b2,
                                  head_ln_g, head_ln_b, head_w, head_b, out);
}